// Round 6
// baseline (501.512 us; speedup 1.0000x reference)
//
#include <hip/hip_runtime.h>

#define LN_EPS 1e-5f
#define NEG_SLOPE 0.2f

typedef __attribute__((ext_vector_type(8))) short short8;
typedef __attribute__((ext_vector_type(4))) float f32x4;
typedef __attribute__((ext_vector_type(16))) float f32x16;

__device__ __forceinline__ unsigned short f2bf(float f) {
  union { float f; unsigned int u; } v;
  v.f = f;
  unsigned int r = v.u + 0x7fffu + ((v.u >> 16) & 1u);
  return (unsigned short)(r >> 16);
}
__device__ __forceinline__ float bf2f(unsigned short u) {
  union { unsigned int u; float f; } v;
  v.u = ((unsigned int)u) << 16;
  return v.f;
}

// ---------------------------------------------------------------------------
// 0) alpha fold (1 block) — must precede k_mega (aqk path reads wqa/wka)
// ---------------------------------------------------------------------------
__global__ __launch_bounds__(256) void k_fold(
    const float* __restrict__ Wq, const float* __restrict__ Wk,
    const float* __restrict__ alphaQ, const float* __restrict__ alphaK,
    float* __restrict__ wqa, float* __restrict__ wka) {
  int t = threadIdx.x;
  for (int h = 0; h < 4; ++h) {
    float sq = 0.f, sk = 0.f;
    for (int od = 0; od < 64; ++od) {
      sq += Wq[t * 256 + h * 64 + od] * alphaQ[h * 64 + od];
      sk += Wk[t * 256 + h * 64 + od] * alphaK[h * 64 + od];
    }
    wqa[t * 4 + h] = sq;
    wka[t * 4 + h] = sk;
  }
}

// ---------------------------------------------------------------------------
// 1) k_mega: blocks 0..2047 = weight transpose-casts; 2048..2143 = zero ideg;
//    2144..8287 = node cast + aQ/aK (one wave per node, node_feat read ONCE)
// ---------------------------------------------------------------------------
__global__ __launch_bounds__(256) void k_mega(
    const float* __restrict__ Wv, const float* __restrict__ gW1,
    const float* __restrict__ gW2, const float* __restrict__ fW1,
    const float* __restrict__ fW2, unsigned short* __restrict__ wvt,
    unsigned short* __restrict__ w1t, unsigned short* __restrict__ w2t,
    unsigned short* __restrict__ fw1t, unsigned short* __restrict__ fw2t,
    int* __restrict__ ideg, int Nn, const float* __restrict__ node_feat,
    unsigned short* __restrict__ nf16, const float* __restrict__ wqa,
    const float* __restrict__ wka, float* __restrict__ aQ,
    float* __restrict__ aK) {
  const int bid = blockIdx.x;
  if (bid < 2048) {  // transpose-cast weights
    int i = bid * 256 + threadIdx.x;
    const float* src;
    unsigned short* dst;
    int K, N, base;
    if (i < 65536) {
      src = Wv; dst = wvt; K = 256; N = 256; base = 0;
    } else if (i < 196608) {
      src = gW1; dst = w1t; K = 256; N = 512; base = 65536;
    } else if (i < 327680) {
      src = gW2; dst = w2t; K = 512; N = 256; base = 196608;
    } else if (i < 458752) {
      src = fW1; dst = fw1t; K = 512; N = 256; base = 327680;
    } else {
      src = fW2; dst = fw2t; K = 256; N = 256; base = 458752;
    }
    int j = i - base;
    int n = j / K, k = j - n * K;
    dst[j] = f2bf(src[(size_t)k * N + n]);
    return;
  }
  if (bid < 2144) {  // zero in-degree array
    int i = (bid - 2048) * 256 + threadIdx.x;
    if (i < Nn) ideg[i] = 0;
    return;
  }
  // cast + aqk: 4 waves per block, one node per wave
  const int n = (bid - 2144) * 4 + (threadIdx.x >> 6);
  const int lane = threadIdx.x & 63;
  f32x4 x = ((const f32x4*)node_feat)[(size_t)n * 64 + lane];
  ushort4 o;
  o.x = f2bf(x.x);
  o.y = f2bf(x.y);
  o.z = f2bf(x.z);
  o.w = f2bf(x.w);
  ((ushort4*)nf16)[(size_t)n * 64 + lane] = o;
  float sq[4], sk[4];
  const int d0 = lane * 4;
#pragma unroll
  for (int h = 0; h < 4; ++h) {
    sq[h] = x.x * wqa[(d0 + 0) * 4 + h] + x.y * wqa[(d0 + 1) * 4 + h] +
            x.z * wqa[(d0 + 2) * 4 + h] + x.w * wqa[(d0 + 3) * 4 + h];
    sk[h] = x.x * wka[(d0 + 0) * 4 + h] + x.y * wka[(d0 + 1) * 4 + h] +
            x.z * wka[(d0 + 2) * 4 + h] + x.w * wka[(d0 + 3) * 4 + h];
  }
#pragma unroll
  for (int off = 32; off; off >>= 1) {
#pragma unroll
    for (int h = 0; h < 4; ++h) {
      sq[h] += __shfl_xor(sq[h], off);
      sk[h] += __shfl_xor(sk[h], off);
    }
  }
  if (lane == 0) {
#pragma unroll
    for (int h = 0; h < 4; ++h) {
      aQ[(size_t)n * 4 + h] = sq[h];
      aK[(size_t)n * 4 + h] = sk[h];
    }
  }
}

// ---------------------------------------------------------------------------
// 2) batched bf16 GEMM, 32x32x16 MFMA, double-buffered LDS + reg prefetch.
//    C[M,N] = A[M,K] @ Bt[N,K]^T ; per-desc runtime relu/bias/outbf.
// ---------------------------------------------------------------------------
struct GDesc {
  const unsigned short* A;
  const unsigned short* Bt;
  const float* bias;  // nullptr = no bias
  void* C;
  int N, K;
  int relu, outbf;
};

__device__ __forceinline__ f32x16 zero16() {
  f32x16 z;
#pragma unroll
  for (int i = 0; i < 16; ++i) z[i] = 0.f;
  return z;
}

__global__ __launch_bounds__(256) void k_gemm2(GDesc d0, GDesc d1, int nb0) {
  __shared__ uint4 As[2][1024];  // [buf][row*8 + (slot ^ (row&7))]
  __shared__ uint4 Bs[2][1024];
  GDesc d = d0;
  int t = blockIdx.x;
  if (t >= nb0) {
    d = d1;
    t -= nb0;
  }
  const int nN = d.N >> 7;
  const int row0 = (t / nN) << 7;
  const int col0 = (t % nN) << 7;
  const int tid = threadIdx.x;
  const int wid = tid >> 6, lane = tid & 63;
  const int wr = wid >> 1, wc = wid & 1;
  const int l31 = lane & 31, lh = lane >> 5;

  f32x16 acc[2][2];
#pragma unroll
  for (int m = 0; m < 2; ++m)
#pragma unroll
    for (int n = 0; n < 2; ++n) acc[m][n] = zero16();

  const int nt = d.K >> 6;
  uint4 ra[4], rb[4];
  // prologue: stage tile 0
#pragma unroll
  for (int c = 0; c < 4; ++c) {
    int idx = c * 256 + tid;
    int row = idx >> 3, slot = idx & 7;
    ra[c] = *(const uint4*)(d.A + (size_t)(row0 + row) * d.K + slot * 8);
    rb[c] = *(const uint4*)(d.Bt + (size_t)(col0 + row) * d.K + slot * 8);
  }
#pragma unroll
  for (int c = 0; c < 4; ++c) {
    int idx = c * 256 + tid;
    int row = idx >> 3, slot = idx & 7;
    int dsti = row * 8 + (slot ^ (row & 7));
    As[0][dsti] = ra[c];
    Bs[0][dsti] = rb[c];
  }
  __syncthreads();

  for (int t0 = 0; t0 < nt; ++t0) {
    const int cur = t0 & 1;
    if (t0 + 1 < nt) {  // prefetch next tile to regs (overlaps MFMA below)
      const int k0 = (t0 + 1) << 6;
#pragma unroll
      for (int c = 0; c < 4; ++c) {
        int idx = c * 256 + tid;
        int row = idx >> 3, slot = idx & 7;
        ra[c] = *(const uint4*)(d.A + (size_t)(row0 + row) * d.K + k0 + slot * 8);
        rb[c] = *(const uint4*)(d.Bt + (size_t)(col0 + row) * d.K + k0 + slot * 8);
      }
    }
#pragma unroll
    for (int kk = 0; kk < 4; ++kk) {
      short8 af[2], bf[2];
      const int kslot = kk * 2 + lh;
#pragma unroll
      for (int m = 0; m < 2; ++m) {
        int row = wr * 64 + m * 32 + l31;
        af[m] = *(const short8*)&As[cur][row * 8 + (kslot ^ (row & 7))];
        int col = wc * 64 + m * 32 + l31;
        bf[m] = *(const short8*)&Bs[cur][col * 8 + (kslot ^ (col & 7))];
      }
#pragma unroll
      for (int m = 0; m < 2; ++m)
#pragma unroll
        for (int n = 0; n < 2; ++n)
          acc[m][n] = __builtin_amdgcn_mfma_f32_32x32x16_bf16(af[m], bf[n],
                                                              acc[m][n], 0, 0, 0);
    }
    if (t0 + 1 < nt) {
#pragma unroll
      for (int c = 0; c < 4; ++c) {
        int idx = c * 256 + tid;
        int row = idx >> 3, slot = idx & 7;
        int dsti = row * 8 + (slot ^ (row & 7));
        As[cur ^ 1][dsti] = ra[c];
        Bs[cur ^ 1][dsti] = rb[c];
      }
      __syncthreads();
    }
  }

  // epilogue: C/D layout row=(r&3)+8*(r>>2)+4*lh, col=l31 per 32x32 tile
#pragma unroll
  for (int n = 0; n < 2; ++n) {
    const int col = col0 + wc * 64 + n * 32 + l31;
    const float bv = d.bias ? d.bias[col] : 0.f;
#pragma unroll
    for (int m = 0; m < 2; ++m) {
#pragma unroll
      for (int r = 0; r < 16; ++r) {
        int row = row0 + wr * 64 + m * 32 + (r & 3) + ((r >> 2) << 3) + (lh << 2);
        float v = acc[m][n][r] + bv;
        if (d.relu) v = fmaxf(v, 0.f);
        if (d.outbf)
          ((unsigned short*)d.C)[(size_t)row * d.N + col] = f2bf(v);
        else
          ((float*)d.C)[(size_t)row * d.N + col] = v;
      }
    }
  }
}

// ---------------------------------------------------------------------------
// 3) MFMA attention (unchanged from round 5)
// ---------------------------------------------------------------------------
__global__ __launch_bounds__(256) void k_attn(
    const float* __restrict__ aQ, const float* __restrict__ aK,
    const unsigned short* __restrict__ Vp16,
    const float* __restrict__ attn_bias, const int* __restrict__ ptr,
    unsigned short* __restrict__ attn16) {
  __shared__ unsigned short Vt[64 * 192];
  __shared__ float aQs[192], aKs[192], sinv[192];
  __shared__ float kmax_s;
  const int b = blockIdx.x, h = blockIdx.y;
  const int n0 = ptr[b];
  const int tid = threadIdx.x;
  const int wid = tid >> 6, lane = tid & 63;

  if (tid < 192) {
    aQs[tid] = aQ[(size_t)(n0 + tid) * 4 + h];
    aKs[tid] = aK[(size_t)(n0 + tid) * 4 + h];
  }
  for (int i = tid; i < 1536; i += 256) {
    int k = i >> 3, cc = (i & 7) << 3;
    short8 v = *(const short8*)(Vp16 + (size_t)(n0 + k) * 256 + h * 64 + cc);
    int ks = k >> 3, kr = k & 7;
#pragma unroll
    for (int jj = 0; jj < 8; ++jj) {
      int c = cc + jj;
      Vt[c * 192 + ((ks ^ (c & 7)) << 3) + kr] = (unsigned short)v[jj];
    }
  }
  __syncthreads();
  if (wid == 0) {
    float m3 = fmaxf(fmaxf(aKs[lane], aKs[lane + 64]), aKs[lane + 128]);
#pragma unroll
    for (int off = 32; off; off >>= 1) m3 = fmaxf(m3, __shfl_xor(m3, off));
    if (lane == 0) kmax_s = m3;
  }
  __syncthreads();
  const float kmax = kmax_s;
  const int fr = lane & 15, fq = lane >> 4;
  const int qbase = wid * 48;

  float aq_m[3], mm[3];
#pragma unroll
  for (int m = 0; m < 3; ++m) {
    float aqv = aQs[qbase + m * 16 + fr];
    aq_m[m] = aqv;
    float t = aqv + kmax;
    mm[m] = t > 0.f ? t : NEG_SLOPE * t;
  }

  f32x4 acc[3][4];
#pragma unroll
  for (int m = 0; m < 3; ++m)
#pragma unroll
    for (int n = 0; n < 4; ++n) acc[m][n] = (f32x4){0.f, 0.f, 0.f, 0.f};
  float psum[3] = {0.f, 0.f, 0.f};

  for (int ks = 0; ks < 6; ++ks) {
    short8 bf[4];
#pragma unroll
    for (int n = 0; n < 4; ++n) {
      int c = n * 16 + fr;
      bf[n] = *(const short8*)&Vt[c * 192 + ((((ks << 2) + fq) ^ (c & 7)) << 3)];
    }
    float ak[8];
#pragma unroll
    for (int j = 0; j < 8; ++j) ak[j] = aKs[(ks << 5) + (fq << 3) + j];
#pragma unroll
    for (int m = 0; m < 3; ++m) {
      short8 af;
      float ps = 0.f;
#pragma unroll
      for (int j = 0; j < 8; ++j) {
        float x = aq_m[m] + ak[j];
        x = x > 0.f ? x : NEG_SLOPE * x;
        float p = __expf(x - mm[m]);
        ps += p;
        af[j] = (short)f2bf(p);
      }
      psum[m] += ps;
#pragma unroll
      for (int n = 0; n < 4; ++n)
        acc[m][n] =
            __builtin_amdgcn_mfma_f32_16x16x32_bf16(af, bf[n], acc[m][n], 0, 0, 0);
    }
  }

#pragma unroll
  for (int m = 0; m < 3; ++m) {
    psum[m] += __shfl_xor(psum[m], 16);
    psum[m] += __shfl_xor(psum[m], 32);
  }
  if (fq == 0) {
#pragma unroll
    for (int m = 0; m < 3; ++m) sinv[qbase + m * 16 + fr] = 1.f / psum[m];
  }
  __syncthreads();

#pragma unroll
  for (int m = 0; m < 3; ++m) {
#pragma unroll
    for (int n = 0; n < 4; ++n) {
      int col = n * 16 + fr;
      float bv = attn_bias[h * 64 + col];
#pragma unroll
      for (int r = 0; r < 4; ++r) {
        int q = qbase + m * 16 + fq * 4 + r;
        float v = acc[m][n][r] * sinv[q] + bv;
        attn16[(size_t)(n0 + q) * 256 + h * 64 + col] = f2bf(v);
      }
    }
  }
}

// ---------------------------------------------------------------------------
// 4) LayerNorm(x + res) -> bf16
// ---------------------------------------------------------------------------
template <bool XBF>
__global__ __launch_bounds__(64) void k_ln(
    const void* __restrict__ xin, const float* __restrict__ res,
    const float* __restrict__ g, const float* __restrict__ bt,
    unsigned short* __restrict__ out, int ostride, int ooff) {
  const int n = blockIdx.x;
  const int lane = threadIdx.x;
  float v0, v1, v2, v3;
  if (XBF) {
    ushort4 xv = *(const ushort4*)((const unsigned short*)xin +
                                   (size_t)n * 256 + lane * 4);
    v0 = bf2f(xv.x);
    v1 = bf2f(xv.y);
    v2 = bf2f(xv.z);
    v3 = bf2f(xv.w);
  } else {
    float4 xv = *(const float4*)((const float*)xin + (size_t)n * 256 + lane * 4);
    v0 = xv.x;
    v1 = xv.y;
    v2 = xv.z;
    v3 = xv.w;
  }
  float4 rv = *(const float4*)(res + (size_t)n * 256 + lane * 4);
  v0 += rv.x;
  v1 += rv.y;
  v2 += rv.z;
  v3 += rv.w;
  float s = v0 + v1 + v2 + v3;
  float ss = v0 * v0 + v1 * v1 + v2 * v2 + v3 * v3;
#pragma unroll
  for (int off = 32; off; off >>= 1) {
    s += __shfl_xor(s, off);
    ss += __shfl_xor(ss, off);
  }
  const float mean = s * (1.f / 256.f);
  const float var = ss * (1.f / 256.f) - mean * mean;
  const float rs = rsqrtf(var + LN_EPS);
  float4 gv = *(const float4*)(g + lane * 4);
  float4 bv = *(const float4*)(bt + lane * 4);
  ushort4 o;
  o.x = f2bf((v0 - mean) * rs * gv.x + bv.x);
  o.y = f2bf((v1 - mean) * rs * gv.y + bv.y);
  o.z = f2bf((v2 - mean) * rs * gv.z + bv.z);
  o.w = f2bf((v3 - mean) * rs * gv.w + bv.w);
  *(ushort4*)(out + (size_t)n * ostride + ooff + lane * 4) = o;
}

// ---------------------------------------------------------------------------
// 5) GIN aggregation via device-built CSR
// ---------------------------------------------------------------------------
__global__ __launch_bounds__(256) void k_deg(const int* __restrict__ ei,
                                             int* __restrict__ deg, int E) {
  int e = blockIdx.x * 256 + threadIdx.x;
  if (e < E) atomicAdd(&deg[ei[e]], 1);
}

__global__ __launch_bounds__(1024) void k_scan(const int* __restrict__ deg,
                                               int* __restrict__ ofs,
                                               int* __restrict__ cursor,
                                               int Nn) {
  __shared__ int part[1024];
  const int t = threadIdx.x;
  const int CH = (Nn + 1023) / 1024;
  const int base = t * CH;
  int s = 0;
  for (int i = 0; i < CH; ++i) s += (base + i < Nn) ? deg[base + i] : 0;
  part[t] = s;
  __syncthreads();
  for (int off = 1; off < 1024; off <<= 1) {
    int v = (t >= off) ? part[t - off] : 0;
    __syncthreads();
    part[t] += v;
    __syncthreads();
  }
  int o = (t == 0) ? 0 : part[t - 1];
  for (int i = 0; i < CH; ++i) {
    if (base + i < Nn) {
      ofs[base + i] = o;
      cursor[base + i] = o;
      o += deg[base + i];
    }
  }
  if (t == 1023) ofs[Nn] = part[1023];
}

__global__ __launch_bounds__(256) void k_scatter(const int* __restrict__ ei,
                                                 int* __restrict__ cursor,
                                                 int2* __restrict__ edges,
                                                 int E) {
  int e = blockIdx.x * 256 + threadIdx.x;
  if (e < E) {
    int src = ei[e];
    int dst = ei[E + e];
    int pos = atomicAdd(&cursor[src], 1);
    edges[pos] = make_int2(e, dst);
  }
}

__global__ __launch_bounds__(64) void k_gather(
    const float* __restrict__ node, const float* __restrict__ ef,
    const int2* __restrict__ edges, const int* __restrict__ ofs,
    const float* __restrict__ eps_p, unsigned short* __restrict__ agg16) {
  const int n = blockIdx.x;
  const int lane = threadIdx.x;
  const int s0 = ofs[n];
  const int s1 = ofs[n + 1];
  const float epl = 1.f + eps_p[0];
  const f32x4* nodev = (const f32x4*)node;
  const f32x4* efv = (const f32x4*)ef;
  f32x4 xv = nodev[(size_t)n * 64 + lane];
  float a0 = epl * xv.x, a1 = epl * xv.y, a2 = epl * xv.z, a3 = epl * xv.w;
  int j = s0;
  for (; j + 4 <= s1; j += 4) {
    int2 ed0 = edges[j], ed1 = edges[j + 1], ed2 = edges[j + 2],
         ed3 = edges[j + 3];
    f32x4 e0 = __builtin_nontemporal_load(&efv[(size_t)ed0.x * 64 + lane]);
    f32x4 e1 = __builtin_nontemporal_load(&efv[(size_t)ed1.x * 64 + lane]);
    f32x4 e2 = __builtin_nontemporal_load(&efv[(size_t)ed2.x * 64 + lane]);
    f32x4 e3 = __builtin_nontemporal_load(&efv[(size_t)ed3.x * 64 + lane]);
    f32x4 m0 = nodev[(size_t)ed0.y * 64 + lane];
    f32x4 m1 = nodev[(size_t)ed1.y * 64 + lane];
    f32x4 m2 = nodev[(size_t)ed2.y * 64 + lane];
    f32x4 m3 = nodev[(size_t)ed3.y * 64 + lane];
    a0 += fmaxf(e0.x + m0.x, 0.f) + fmaxf(e1.x + m1.x, 0.f) +
          fmaxf(e2.x + m2.x, 0.f) + fmaxf(e3.x + m3.x, 0.f);
    a1 += fmaxf(e0.y + m0.y, 0.f) + fmaxf(e1.y + m1.y, 0.f) +
          fmaxf(e2.y + m2.y, 0.f) + fmaxf(e3.y + m3.y, 0.f);
    a2 += fmaxf(e0.z + m0.z, 0.f) + fmaxf(e1.z + m1.z, 0.f) +
          fmaxf(e2.z + m2.z, 0.f) + fmaxf(e3.z + m3.z, 0.f);
    a3 += fmaxf(e0.w + m0.w, 0.f) + fmaxf(e1.w + m1.w, 0.f) +
          fmaxf(e2.w + m2.w, 0.f) + fmaxf(e3.w + m3.w, 0.f);
  }
  for (; j < s1; ++j) {
    int2 ed = edges[j];
    f32x4 ev = __builtin_nontemporal_load(&efv[(size_t)ed.x * 64 + lane]);
    f32x4 mv = nodev[(size_t)ed.y * 64 + lane];
    a0 += fmaxf(ev.x + mv.x, 0.f);
    a1 += fmaxf(ev.y + mv.y, 0.f);
    a2 += fmaxf(ev.z + mv.z, 0.f);
    a3 += fmaxf(ev.w + mv.w, 0.f);
  }
  ushort4 o;
  o.x = f2bf(a0);
  o.y = f2bf(a1);
  o.z = f2bf(a2);
  o.w = f2bf(a3);
  *(ushort4*)(agg16 + (size_t)n * 256 + lane * 4) = o;
}

// ---------------------------------------------------------------------------
extern "C" void kernel_launch(void* const* d_in, const int* in_sizes, int n_in,
                              void* d_out, int out_size, void* d_ws,
                              size_t ws_size, hipStream_t stream) {
  const float* node_feat = (const float*)d_in[0];
  const float* edge_feat = (const float*)d_in[2];
  const int* edge_index = (const int*)d_in[3];
  const int* ptr = (const int*)d_in[5];
  const float* Wq = (const float*)d_in[6];
  const float* Wk = (const float*)d_in[7];
  const float* Wv = (const float*)d_in[8];
  const float* alphaQ = (const float*)d_in[9];
  const float* alphaK = (const float*)d_in[10];
  const float* attn_bias = (const float*)d_in[11];
  const float* gin_eps = (const float*)d_in[12];
  const float* gin_W1 = (const float*)d_in[13];
  const float* gin_b1 = (const float*)d_in[14];
  const float* gin_W2 = (const float*)d_in[15];
  const float* gin_b2 = (const float*)d_in[16];
  const float* ln1_g = (const float*)d_in[17];
  const float* ln1_b = (const float*)d_in[18];
  const float* ln2_g = (const float*)d_in[19];
  const float* ln2_b = (const float*)d_in[20];
  const float* ff_W1 = (const float*)d_in[21];
  const float* ff_b1 = (const float*)d_in[22];
  const float* ff_W2 = (const float*)d_in[23];
  const float* ff_b2 = (const float*)d_in[24];

  const int N = in_sizes[0] / 256;  // 24576
  const int E = in_sizes[2] / 256;  // 393216
  const int B = in_sizes[5] - 1;    // 128

  // workspace layout
  float* ws = (float*)d_ws;
  float* buf0 = ws;                                    // gin fc2 out [N*256] f32
  unsigned short* x2_16 = (unsigned short*)(buf0 + (size_t)N * 256);  // [N*512]
  unsigned short* agg16 = x2_16 + (size_t)N * 512;     // [N*256]
  unsigned short* t1_16 = agg16 + (size_t)N * 256;     // [N*512]
  unsigned short* h1_16 = t1_16 + (size_t)N * 512;     // [N*256]
  unsigned short* nf16 = h1_16 + (size_t)N * 256;      // [N*256]
  unsigned short* vp16 = nf16 + (size_t)N * 256;       // [N*256]
  unsigned short* at16 = vp16 + (size_t)N * 256;       // [N*256]
  unsigned short* wvt = at16 + (size_t)N * 256;        // [256*256]
  unsigned short* w1t = wvt + 65536;                   // [512*256]
  unsigned short* w2t = w1t + 131072;                  // [256*512]
  unsigned short* ffw1t = w2t + 131072;                // [256*512]
  unsigned short* ffw2t = ffw1t + 131072;              // [256*256]
  float* wqa = (float*)(ffw2t + 65536);                // [1024]
  float* wka = wqa + 1024;
  float* aQ = wka + 1024;                  // [N*4]
  float* aK = aQ + (size_t)N * 4;          // [N*4]
  int* ideg = (int*)(aK + (size_t)N * 4);  // [N]
  int* ofs = ideg + N;                     // [N+2]
  int* cursor = ofs + N + 2;               // [N]
  int2* edges = (int2*)(cursor + N);       // [E]
  size_t need = (size_t)N * 256 * 4 + (size_t)N * 2304 * 2 + 1100000 +
                (size_t)N * 8 * 4 + (size_t)N * 16 + (size_t)E * 8 + 8192;
  if (ws_size < need) return;

  // --- prep: fold, then mega (weights T-cast + ideg zero + cast/aqk) ---
  k_fold<<<1, 256, 0, stream>>>(Wq, Wk, alphaQ, alphaK, wqa, wka);
  k_mega<<<2144 + N / 4, 256, 0, stream>>>(
      Wv, gin_W1, gin_W2, ff_W1, ff_W2, wvt, w1t, w2t, ffw1t, ffw2t, ideg, N,
      node_feat, nf16, wqa, wka, aQ, aK);

  // --- CSR build + gather ---
  k_deg<<<(E + 255) / 256, 256, 0, stream>>>(edge_index, ideg, E);
  k_scan<<<1, 1024, 0, stream>>>(ideg, ofs, cursor, N);
  k_scatter<<<(E + 255) / 256, 256, 0, stream>>>(edge_index, cursor, edges, E);
  k_gather<<<N, 64, 0, stream>>>(node_feat, edge_feat, edges, ofs, gin_eps,
                                 agg16);

  // --- batched GEMM: Vp (attn branch) || gin fc1 ---
  GDesc dVp{nf16, wvt, nullptr, vp16, 256, 256, 0, 1};
  GDesc dF1{agg16, w1t, gin_b1, t1_16, 512, 256, 1, 1};
  const int nbVp = (N / 128) * 2, nbF1 = (N / 128) * 4;
  k_gemm2<<<nbVp + nbF1, 256, 0, stream>>>(dVp, dF1, nbVp);

  // --- attention ---
  k_attn<<<dim3(B, 4), 256, 0, stream>>>(aQ, aK, vp16, attn_bias, ptr, at16);
  k_ln<true><<<N, 64, 0, stream>>>(at16, node_feat, ln1_g, ln1_b, x2_16, 512,
                                   256);

  // --- gin fc2 + LN2 ---
  GDesc dF2{t1_16, w2t, gin_b2, buf0, 256, 512, 0, 0};
  k_gemm2<<<(N / 128) * 2, 256, 0, stream>>>(dF2, dF2, 1 << 30);
  k_ln<false><<<N, 64, 0, stream>>>(buf0, node_feat, ln2_g, ln2_b, x2_16, 512,
                                    0);

  // --- FF head ---
  GDesc dX1{x2_16, ffw1t, ff_b1, h1_16, 256, 512, 1, 1};
  k_gemm2<<<(N / 128) * 2, 256, 0, stream>>>(dX1, dX1, 1 << 30);
  GDesc dX2{h1_16, ffw2t, ff_b2, d_out, 256, 256, 0, 0};
  k_gemm2<<<(N / 128) * 2, 256, 0, stream>>>(dX2, dX2, 1 << 30);
}

// Round 7
// 343.681 us; speedup vs baseline: 1.4592x; 1.4592x over previous
//
#include <hip/hip_runtime.h>

#define LN_EPS 1e-5f
#define NEG_SLOPE 0.2f

typedef __attribute__((ext_vector_type(8))) short short8;
typedef __attribute__((ext_vector_type(4))) float f32x4;

__device__ __forceinline__ unsigned short f2bf(float f) {
  union { float f; unsigned int u; } v;
  v.f = f;
  unsigned int r = v.u + 0x7fffu + ((v.u >> 16) & 1u);
  return (unsigned short)(r >> 16);
}
__device__ __forceinline__ float bf2f(unsigned short u) {
  union { unsigned int u; float f; } v;
  v.u = ((unsigned int)u) << 16;
  return v.f;
}

// ---------------------------------------------------------------------------
// 0) alpha fold (1 block) — must precede k_mega (aqk path reads wqa/wka)
// ---------------------------------------------------------------------------
__global__ __launch_bounds__(256) void k_fold(
    const float* __restrict__ Wq, const float* __restrict__ Wk,
    const float* __restrict__ alphaQ, const float* __restrict__ alphaK,
    float* __restrict__ wqa, float* __restrict__ wka) {
  int t = threadIdx.x;
  for (int h = 0; h < 4; ++h) {
    float sq = 0.f, sk = 0.f;
    for (int od = 0; od < 64; ++od) {
      sq += Wq[t * 256 + h * 64 + od] * alphaQ[h * 64 + od];
      sk += Wk[t * 256 + h * 64 + od] * alphaK[h * 64 + od];
    }
    wqa[t * 4 + h] = sq;
    wka[t * 4 + h] = sk;
  }
}

// ---------------------------------------------------------------------------
// 1) k_mega: blocks 0..2047 weight T-casts; 2048..2143 zero ideg;
//    2144.. node cast + aQ/aK (node_feat read once)
// ---------------------------------------------------------------------------
__global__ __launch_bounds__(256) void k_mega(
    const float* __restrict__ Wv, const float* __restrict__ gW1,
    const float* __restrict__ gW2, const float* __restrict__ fW1,
    const float* __restrict__ fW2, unsigned short* __restrict__ wvt,
    unsigned short* __restrict__ w1t, unsigned short* __restrict__ w2t,
    unsigned short* __restrict__ fw1t, unsigned short* __restrict__ fw2t,
    int* __restrict__ ideg, int Nn, const float* __restrict__ node_feat,
    unsigned short* __restrict__ nf16, const float* __restrict__ wqa,
    const float* __restrict__ wka, float* __restrict__ aQ,
    float* __restrict__ aK) {
  const int bid = blockIdx.x;
  if (bid < 2048) {
    int i = bid * 256 + threadIdx.x;
    const float* src;
    unsigned short* dst;
    int K, N, base;
    if (i < 65536) {
      src = Wv; dst = wvt; K = 256; N = 256; base = 0;
    } else if (i < 196608) {
      src = gW1; dst = w1t; K = 256; N = 512; base = 65536;
    } else if (i < 327680) {
      src = gW2; dst = w2t; K = 512; N = 256; base = 196608;
    } else if (i < 458752) {
      src = fW1; dst = fw1t; K = 512; N = 256; base = 327680;
    } else {
      src = fW2; dst = fw2t; K = 256; N = 256; base = 458752;
    }
    int j = i - base;
    int n = j / K, k = j - n * K;
    dst[j] = f2bf(src[(size_t)k * N + n]);
    return;
  }
  if (bid < 2144) {
    int i = (bid - 2048) * 256 + threadIdx.x;
    if (i < Nn) ideg[i] = 0;
    return;
  }
  const int n = (bid - 2144) * 4 + (threadIdx.x >> 6);
  const int lane = threadIdx.x & 63;
  f32x4 x = ((const f32x4*)node_feat)[(size_t)n * 64 + lane];
  ushort4 o;
  o.x = f2bf(x.x);
  o.y = f2bf(x.y);
  o.z = f2bf(x.z);
  o.w = f2bf(x.w);
  ((ushort4*)nf16)[(size_t)n * 64 + lane] = o;
  float sq[4], sk[4];
  const int d0 = lane * 4;
#pragma unroll
  for (int h = 0; h < 4; ++h) {
    sq[h] = x.x * wqa[(d0 + 0) * 4 + h] + x.y * wqa[(d0 + 1) * 4 + h] +
            x.z * wqa[(d0 + 2) * 4 + h] + x.w * wqa[(d0 + 3) * 4 + h];
    sk[h] = x.x * wka[(d0 + 0) * 4 + h] + x.y * wka[(d0 + 1) * 4 + h] +
            x.z * wka[(d0 + 2) * 4 + h] + x.w * wka[(d0 + 3) * 4 + h];
  }
#pragma unroll
  for (int off = 32; off; off >>= 1) {
#pragma unroll
    for (int h = 0; h < 4; ++h) {
      sq[h] += __shfl_xor(sq[h], off);
      sk[h] += __shfl_xor(sk[h], off);
    }
  }
  if (lane == 0) {
#pragma unroll
    for (int h = 0; h < 4; ++h) {
      aQ[(size_t)n * 4 + h] = sq[h];
      aK[(size_t)n * 4 + h] = sk[h];
    }
  }
}

// ---------------------------------------------------------------------------
// 2) bf16 MFMA GEMM, BM=64 x BN=128, BK=64, 16x16x32, single-buffer LDS (24KB)
//    4 waves (2x2), wave patch 32x64. C[M,N] = A[M,K] @ Bt[N,K]^T
// ---------------------------------------------------------------------------
template <bool RELU, bool BIAS, bool OUTBF>
__global__ __launch_bounds__(256) void k_gemm16(
    const unsigned short* __restrict__ A, const unsigned short* __restrict__ Bt,
    const float* __restrict__ bias, void* __restrict__ Cv, int M, int N,
    int K) {
  __shared__ uint4 As[512];   // 64 rows x 8 slots, slot ^= (row&7)
  __shared__ uint4 Bs[1024];  // 128 rows x 8 slots
  const int tid = threadIdx.x;
  const int wid = tid >> 6;
  const int lane = tid & 63;
  const int row0 = blockIdx.x * 64;
  const int col0 = blockIdx.y * 128;
  const int wr = wid >> 1;   // 0..1 (32 rows each)
  const int wc = wid & 1;    // 0..1 (64 cols each)
  const int fr = lane & 15;
  const int fq = lane >> 4;

  f32x4 acc[2][4];
#pragma unroll
  for (int m = 0; m < 2; ++m)
#pragma unroll
    for (int n = 0; n < 4; ++n) acc[m][n] = (f32x4){0.f, 0.f, 0.f, 0.f};

  for (int k0 = 0; k0 < K; k0 += 64) {
    __syncthreads();
#pragma unroll
    for (int c = 0; c < 2; ++c) {  // A: 512 slots / 256 threads
      int idx = c * 256 + tid;
      int row = idx >> 3, slot = idx & 7;
      As[row * 8 + (slot ^ (row & 7))] =
          *(const uint4*)(A + (size_t)(row0 + row) * K + k0 + slot * 8);
    }
#pragma unroll
    for (int c = 0; c < 4; ++c) {  // B: 1024 slots
      int idx = c * 256 + tid;
      int row = idx >> 3, slot = idx & 7;
      Bs[row * 8 + (slot ^ (row & 7))] =
          *(const uint4*)(Bt + (size_t)(col0 + row) * K + k0 + slot * 8);
    }
    __syncthreads();
#pragma unroll
    for (int kk = 0; kk < 2; ++kk) {
      short8 af[2], bfr[4];
#pragma unroll
      for (int m = 0; m < 2; ++m) {
        int row = wr * 32 + m * 16 + fr;
        af[m] = *(const short8*)&As[row * 8 + ((kk * 4 + fq) ^ (row & 7))];
      }
#pragma unroll
      for (int n = 0; n < 4; ++n) {
        int col = wc * 64 + n * 16 + fr;
        bfr[n] = *(const short8*)&Bs[col * 8 + ((kk * 4 + fq) ^ (col & 7))];
      }
#pragma unroll
      for (int m = 0; m < 2; ++m)
#pragma unroll
        for (int n = 0; n < 4; ++n)
          acc[m][n] = __builtin_amdgcn_mfma_f32_16x16x32_bf16(af[m], bfr[n],
                                                              acc[m][n], 0, 0, 0);
    }
  }

#pragma unroll
  for (int n = 0; n < 4; ++n) {
    const int col = col0 + wc * 64 + n * 16 + fr;
    const float bv = BIAS ? bias[col] : 0.f;
#pragma unroll
    for (int m = 0; m < 2; ++m) {
#pragma unroll
      for (int r = 0; r < 4; ++r) {
        int row = row0 + wr * 32 + m * 16 + fq * 4 + r;
        float v = acc[m][n][r];
        if (BIAS) v += bv;
        if (RELU) v = fmaxf(v, 0.f);
        if (OUTBF)
          ((unsigned short*)Cv)[(size_t)row * N + col] = f2bf(v);
        else
          ((float*)Cv)[(size_t)row * N + col] = v;
      }
    }
  }
}

// ---------------------------------------------------------------------------
// 3) MFMA attention (proven round-5 version)
// ---------------------------------------------------------------------------
__global__ __launch_bounds__(256) void k_attn(
    const float* __restrict__ aQ, const float* __restrict__ aK,
    const unsigned short* __restrict__ Vp16,
    const float* __restrict__ attn_bias, const int* __restrict__ ptr,
    unsigned short* __restrict__ attn16) {
  __shared__ unsigned short Vt[64 * 192];
  __shared__ float aQs[192], aKs[192], sinv[192];
  __shared__ float kmax_s;
  const int b = blockIdx.x, h = blockIdx.y;
  const int n0 = ptr[b];
  const int tid = threadIdx.x;
  const int wid = tid >> 6, lane = tid & 63;

  if (tid < 192) {
    aQs[tid] = aQ[(size_t)(n0 + tid) * 4 + h];
    aKs[tid] = aK[(size_t)(n0 + tid) * 4 + h];
  }
  for (int i = tid; i < 1536; i += 256) {
    int k = i >> 3, cc = (i & 7) << 3;
    short8 v = *(const short8*)(Vp16 + (size_t)(n0 + k) * 256 + h * 64 + cc);
    int ks = k >> 3, kr = k & 7;
#pragma unroll
    for (int jj = 0; jj < 8; ++jj) {
      int c = cc + jj;
      Vt[c * 192 + ((ks ^ (c & 7)) << 3) + kr] = (unsigned short)v[jj];
    }
  }
  __syncthreads();
  if (wid == 0) {
    float m3 = fmaxf(fmaxf(aKs[lane], aKs[lane + 64]), aKs[lane + 128]);
#pragma unroll
    for (int off = 32; off; off >>= 1) m3 = fmaxf(m3, __shfl_xor(m3, off));
    if (lane == 0) kmax_s = m3;
  }
  __syncthreads();
  const float kmax = kmax_s;
  const int fr = lane & 15, fq = lane >> 4;
  const int qbase = wid * 48;

  float aq_m[3], mm[3];
#pragma unroll
  for (int m = 0; m < 3; ++m) {
    float aqv = aQs[qbase + m * 16 + fr];
    aq_m[m] = aqv;
    float t = aqv + kmax;
    mm[m] = t > 0.f ? t : NEG_SLOPE * t;
  }

  f32x4 acc[3][4];
#pragma unroll
  for (int m = 0; m < 3; ++m)
#pragma unroll
    for (int n = 0; n < 4; ++n) acc[m][n] = (f32x4){0.f, 0.f, 0.f, 0.f};
  float psum[3] = {0.f, 0.f, 0.f};

  for (int ks = 0; ks < 6; ++ks) {
    short8 bf[4];
#pragma unroll
    for (int n = 0; n < 4; ++n) {
      int c = n * 16 + fr;
      bf[n] = *(const short8*)&Vt[c * 192 + ((((ks << 2) + fq) ^ (c & 7)) << 3)];
    }
    float ak[8];
#pragma unroll
    for (int j = 0; j < 8; ++j) ak[j] = aKs[(ks << 5) + (fq << 3) + j];
#pragma unroll
    for (int m = 0; m < 3; ++m) {
      short8 af;
      float ps = 0.f;
#pragma unroll
      for (int j = 0; j < 8; ++j) {
        float x = aq_m[m] + ak[j];
        x = x > 0.f ? x : NEG_SLOPE * x;
        float p = __expf(x - mm[m]);
        ps += p;
        af[j] = (short)f2bf(p);
      }
      psum[m] += ps;
#pragma unroll
      for (int n = 0; n < 4; ++n)
        acc[m][n] =
            __builtin_amdgcn_mfma_f32_16x16x32_bf16(af, bf[n], acc[m][n], 0, 0, 0);
    }
  }

#pragma unroll
  for (int m = 0; m < 3; ++m) {
    psum[m] += __shfl_xor(psum[m], 16);
    psum[m] += __shfl_xor(psum[m], 32);
  }
  if (fq == 0) {
#pragma unroll
    for (int m = 0; m < 3; ++m) sinv[qbase + m * 16 + fr] = 1.f / psum[m];
  }
  __syncthreads();

#pragma unroll
  for (int m = 0; m < 3; ++m) {
#pragma unroll
    for (int n = 0; n < 4; ++n) {
      int col = n * 16 + fr;
      float bv = attn_bias[h * 64 + col];
#pragma unroll
      for (int r = 0; r < 4; ++r) {
        int q = qbase + m * 16 + fq * 4 + r;
        float v = acc[m][n][r] * sinv[q] + bv;
        attn16[(size_t)(n0 + q) * 256 + h * 64 + col] = f2bf(v);
      }
    }
  }
}

// ---------------------------------------------------------------------------
// 4) LayerNorm(x + res) -> bf16
// ---------------------------------------------------------------------------
template <bool XBF>
__global__ __launch_bounds__(64) void k_ln(
    const void* __restrict__ xin, const float* __restrict__ res,
    const float* __restrict__ g, const float* __restrict__ bt,
    unsigned short* __restrict__ out, int ostride, int ooff) {
  const int n = blockIdx.x;
  const int lane = threadIdx.x;
  float v0, v1, v2, v3;
  if (XBF) {
    ushort4 xv = *(const ushort4*)((const unsigned short*)xin +
                                   (size_t)n * 256 + lane * 4);
    v0 = bf2f(xv.x);
    v1 = bf2f(xv.y);
    v2 = bf2f(xv.z);
    v3 = bf2f(xv.w);
  } else {
    float4 xv = *(const float4*)((const float*)xin + (size_t)n * 256 + lane * 4);
    v0 = xv.x;
    v1 = xv.y;
    v2 = xv.z;
    v3 = xv.w;
  }
  float4 rv = *(const float4*)(res + (size_t)n * 256 + lane * 4);
  v0 += rv.x;
  v1 += rv.y;
  v2 += rv.z;
  v3 += rv.w;
  float s = v0 + v1 + v2 + v3;
  float ss = v0 * v0 + v1 * v1 + v2 * v2 + v3 * v3;
#pragma unroll
  for (int off = 32; off; off >>= 1) {
    s += __shfl_xor(s, off);
    ss += __shfl_xor(ss, off);
  }
  const float mean = s * (1.f / 256.f);
  const float var = ss * (1.f / 256.f) - mean * mean;
  const float rs = rsqrtf(var + LN_EPS);
  float4 gv = *(const float4*)(g + lane * 4);
  float4 bv = *(const float4*)(bt + lane * 4);
  ushort4 o;
  o.x = f2bf((v0 - mean) * rs * gv.x + bv.x);
  o.y = f2bf((v1 - mean) * rs * gv.y + bv.y);
  o.z = f2bf((v2 - mean) * rs * gv.z + bv.z);
  o.w = f2bf((v3 - mean) * rs * gv.w + bv.w);
  *(ushort4*)(out + (size_t)n * ostride + ooff + lane * 4) = o;
}

// ---------------------------------------------------------------------------
// 5) GIN aggregation via device-built CSR
// ---------------------------------------------------------------------------
__global__ __launch_bounds__(256) void k_deg(const int* __restrict__ ei,
                                             int* __restrict__ deg, int E) {
  int e = blockIdx.x * 256 + threadIdx.x;
  if (e < E) atomicAdd(&deg[ei[e]], 1);
}

__global__ __launch_bounds__(1024) void k_scan(const int* __restrict__ deg,
                                               int* __restrict__ ofs,
                                               int* __restrict__ cursor,
                                               int Nn) {
  __shared__ int part[1024];
  const int t = threadIdx.x;
  const int CH = (Nn + 1023) / 1024;
  const int base = t * CH;
  int s = 0;
  for (int i = 0; i < CH; ++i) s += (base + i < Nn) ? deg[base + i] : 0;
  part[t] = s;
  __syncthreads();
  for (int off = 1; off < 1024; off <<= 1) {
    int v = (t >= off) ? part[t - off] : 0;
    __syncthreads();
    part[t] += v;
    __syncthreads();
  }
  int o = (t == 0) ? 0 : part[t - 1];
  for (int i = 0; i < CH; ++i) {
    if (base + i < Nn) {
      ofs[base + i] = o;
      cursor[base + i] = o;
      o += deg[base + i];
    }
  }
  if (t == 1023) ofs[Nn] = part[1023];
}

__global__ __launch_bounds__(256) void k_scatter(const int* __restrict__ ei,
                                                 int* __restrict__ cursor,
                                                 int2* __restrict__ edges,
                                                 int E) {
  int e = blockIdx.x * 256 + threadIdx.x;
  if (e < E) {
    int src = ei[e];
    int dst = ei[E + e];
    int pos = atomicAdd(&cursor[src], 1);
    edges[pos] = make_int2(e, dst);
  }
}

__global__ __launch_bounds__(64) void k_gather(
    const float* __restrict__ node, const float* __restrict__ ef,
    const int2* __restrict__ edges, const int* __restrict__ ofs,
    const float* __restrict__ eps_p, unsigned short* __restrict__ agg16) {
  const int n = blockIdx.x;
  const int lane = threadIdx.x;
  const int s0 = ofs[n];
  const int s1 = ofs[n + 1];
  const float epl = 1.f + eps_p[0];
  const f32x4* nodev = (const f32x4*)node;
  const f32x4* efv = (const f32x4*)ef;
  f32x4 xv = nodev[(size_t)n * 64 + lane];
  float a0 = epl * xv.x, a1 = epl * xv.y, a2 = epl * xv.z, a3 = epl * xv.w;
  int j = s0;
  for (; j + 4 <= s1; j += 4) {
    int2 ed0 = edges[j], ed1 = edges[j + 1], ed2 = edges[j + 2],
         ed3 = edges[j + 3];
    f32x4 e0 = __builtin_nontemporal_load(&efv[(size_t)ed0.x * 64 + lane]);
    f32x4 e1 = __builtin_nontemporal_load(&efv[(size_t)ed1.x * 64 + lane]);
    f32x4 e2 = __builtin_nontemporal_load(&efv[(size_t)ed2.x * 64 + lane]);
    f32x4 e3 = __builtin_nontemporal_load(&efv[(size_t)ed3.x * 64 + lane]);
    f32x4 m0 = nodev[(size_t)ed0.y * 64 + lane];
    f32x4 m1 = nodev[(size_t)ed1.y * 64 + lane];
    f32x4 m2 = nodev[(size_t)ed2.y * 64 + lane];
    f32x4 m3 = nodev[(size_t)ed3.y * 64 + lane];
    a0 += fmaxf(e0.x + m0.x, 0.f) + fmaxf(e1.x + m1.x, 0.f) +
          fmaxf(e2.x + m2.x, 0.f) + fmaxf(e3.x + m3.x, 0.f);
    a1 += fmaxf(e0.y + m0.y, 0.f) + fmaxf(e1.y + m1.y, 0.f) +
          fmaxf(e2.y + m2.y, 0.f) + fmaxf(e3.y + m3.y, 0.f);
    a2 += fmaxf(e0.z + m0.z, 0.f) + fmaxf(e1.z + m1.z, 0.f) +
          fmaxf(e2.z + m2.z, 0.f) + fmaxf(e3.z + m3.z, 0.f);
    a3 += fmaxf(e0.w + m0.w, 0.f) + fmaxf(e1.w + m1.w, 0.f) +
          fmaxf(e2.w + m2.w, 0.f) + fmaxf(e3.w + m3.w, 0.f);
  }
  for (; j < s1; ++j) {
    int2 ed = edges[j];
    f32x4 ev = __builtin_nontemporal_load(&efv[(size_t)ed.x * 64 + lane]);
    f32x4 mv = nodev[(size_t)ed.y * 64 + lane];
    a0 += fmaxf(ev.x + mv.x, 0.f);
    a1 += fmaxf(ev.y + mv.y, 0.f);
    a2 += fmaxf(ev.z + mv.z, 0.f);
    a3 += fmaxf(ev.w + mv.w, 0.f);
  }
  ushort4 o;
  o.x = f2bf(a0);
  o.y = f2bf(a1);
  o.z = f2bf(a2);
  o.w = f2bf(a3);
  *(ushort4*)(agg16 + (size_t)n * 256 + lane * 4) = o;
}

// ---------------------------------------------------------------------------
extern "C" void kernel_launch(void* const* d_in, const int* in_sizes, int n_in,
                              void* d_out, int out_size, void* d_ws,
                              size_t ws_size, hipStream_t stream) {
  const float* node_feat = (const float*)d_in[0];
  const float* edge_feat = (const float*)d_in[2];
  const int* edge_index = (const int*)d_in[3];
  const int* ptr = (const int*)d_in[5];
  const float* Wq = (const float*)d_in[6];
  const float* Wk = (const float*)d_in[7];
  const float* Wv = (const float*)d_in[8];
  const float* alphaQ = (const float*)d_in[9];
  const float* alphaK = (const float*)d_in[10];
  const float* attn_bias = (const float*)d_in[11];
  const float* gin_eps = (const float*)d_in[12];
  const float* gin_W1 = (const float*)d_in[13];
  const float* gin_b1 = (const float*)d_in[14];
  const float* gin_W2 = (const float*)d_in[15];
  const float* gin_b2 = (const float*)d_in[16];
  const float* ln1_g = (const float*)d_in[17];
  const float* ln1_b = (const float*)d_in[18];
  const float* ln2_g = (const float*)d_in[19];
  const float* ln2_b = (const float*)d_in[20];
  const float* ff_W1 = (const float*)d_in[21];
  const float* ff_b1 = (const float*)d_in[22];
  const float* ff_W2 = (const float*)d_in[23];
  const float* ff_b2 = (const float*)d_in[24];

  const int N = in_sizes[0] / 256;  // 24576
  const int E = in_sizes[2] / 256;  // 393216
  const int B = in_sizes[5] - 1;    // 128

  // workspace layout
  float* ws = (float*)d_ws;
  float* buf0 = ws;                                    // gin fc2 out [N*256] f32
  unsigned short* x2_16 = (unsigned short*)(buf0 + (size_t)N * 256);  // [N*512]
  unsigned short* agg16 = x2_16 + (size_t)N * 512;     // [N*256]
  unsigned short* t1_16 = agg16 + (size_t)N * 256;     // [N*512]
  unsigned short* h1_16 = t1_16 + (size_t)N * 512;     // [N*256]
  unsigned short* nf16 = h1_16 + (size_t)N * 256;      // [N*256]
  unsigned short* vp16 = nf16 + (size_t)N * 256;       // [N*256]
  unsigned short* at16 = vp16 + (size_t)N * 256;       // [N*256]
  unsigned short* wvt = at16 + (size_t)N * 256;        // [256*256]
  unsigned short* w1t = wvt + 65536;                   // [512*256]
  unsigned short* w2t = w1t + 131072;                  // [256*512]
  unsigned short* ffw1t = w2t + 131072;                // [256*512]
  unsigned short* ffw2t = ffw1t + 131072;              // [256*256]
  float* wqa = (float*)(ffw2t + 65536);                // [1024]
  float* wka = wqa + 1024;
  float* aQ = wka + 1024;                  // [N*4]
  float* aK = aQ + (size_t)N * 4;          // [N*4]
  int* ideg = (int*)(aK + (size_t)N * 4);  // [N]
  int* ofs = ideg + N;                     // [N+2]
  int* cursor = ofs + N + 2;               // [N]
  int2* edges = (int2*)(cursor + N);       // [E]
  size_t need = (size_t)N * 256 * 4 + (size_t)N * 2304 * 2 + 1100000 +
                (size_t)N * 8 * 4 + (size_t)N * 16 + (size_t)E * 8 + 8192;
  if (ws_size < need) return;

  // --- prep ---
  k_fold<<<1, 256, 0, stream>>>(Wq, Wk, alphaQ, alphaK, wqa, wka);
  k_mega<<<2144 + N / 4, 256, 0, stream>>>(
      Wv, gin_W1, gin_W2, ff_W1, ff_W2, wvt, w1t, w2t, ffw1t, ffw2t, ideg, N,
      node_feat, nf16, wqa, wka, aQ, aK);

  // --- attention branch ---
  k_gemm16<false, false, true><<<dim3(N / 64, 2), 256, 0, stream>>>(
      nf16, wvt, nullptr, vp16, N, 256, 256);  // Vp (bf16 out)
  k_attn<<<dim3(B, 4), 256, 0, stream>>>(aQ, aK, vp16, attn_bias, ptr, at16);
  k_ln<true><<<N, 64, 0, stream>>>(at16, node_feat, ln1_g, ln1_b, x2_16, 512,
                                   256);

  // --- GIN branch: CSR build + gather ---
  k_deg<<<(E + 255) / 256, 256, 0, stream>>>(edge_index, ideg, E);
  k_scan<<<1, 1024, 0, stream>>>(ideg, ofs, cursor, N);
  k_scatter<<<(E + 255) / 256, 256, 0, stream>>>(edge_index, cursor, edges, E);
  k_gather<<<N, 64, 0, stream>>>(node_feat, edge_feat, edges, ofs, gin_eps,
                                 agg16);
  k_gemm16<true, true, true><<<dim3(N / 64, 4), 256, 0, stream>>>(
      agg16, w1t, gin_b1, t1_16, N, 512, 256);  // gin fc1
  k_gemm16<false, true, false><<<dim3(N / 64, 2), 256, 0, stream>>>(
      t1_16, w2t, gin_b2, buf0, N, 256, 512);   // gin fc2
  k_ln<false><<<N, 64, 0, stream>>>(buf0, node_feat, ln2_g, ln2_b, x2_16, 512,
                                    0);

  // --- FF head ---
  k_gemm16<true, true, true><<<dim3(N / 64, 2), 256, 0, stream>>>(
      x2_16, ffw1t, ff_b1, h1_16, N, 256, 512);  // ff fc1
  k_gemm16<false, true, false><<<dim3(N / 64, 2), 256, 0, stream>>>(
      h1_16, ffw2t, ff_b2, (float*)d_out, N, 256, 256);  // ff fc2
}

// Round 8
// 334.727 us; speedup vs baseline: 1.4983x; 1.0268x over previous
//
#include <hip/hip_runtime.h>

#define LN_EPS 1e-5f
#define NEG_SLOPE 0.2f

typedef __attribute__((ext_vector_type(8))) short short8;
typedef __attribute__((ext_vector_type(4))) float f32x4;

__device__ __forceinline__ unsigned short f2bf(float f) {
  union { float f; unsigned int u; } v;
  v.f = f;
  unsigned int r = v.u + 0x7fffu + ((v.u >> 16) & 1u);
  return (unsigned short)(r >> 16);
}
__device__ __forceinline__ float bf2f(unsigned short u) {
  union { unsigned int u; float f; } v;
  v.u = ((unsigned int)u) << 16;
  return v.f;
}

// ---------------------------------------------------------------------------
// GEMM role: BM=64 x BN=128, BK=64, 16x16x32 MFMA, 24KB LDS, XOR swizzle.
// t = flattened tile id (row-major over [M/64][N/128]).
// ---------------------------------------------------------------------------
template <bool RELU, bool BIAS, bool OUTBF>
__device__ __forceinline__ void gemm_role(
    int t, char* smemc, const unsigned short* __restrict__ A,
    const unsigned short* __restrict__ Bt, const float* __restrict__ bias,
    void* __restrict__ Cv, int N, int K) {
  uint4* As = (uint4*)smemc;        // 512 slots
  uint4* Bs = (uint4*)smemc + 512;  // 1024 slots
  const int tid = threadIdx.x;
  const int wid = tid >> 6, lane = tid & 63;
  const int nC = N >> 7;
  const int row0 = (t / nC) << 6;
  const int col0 = (t % nC) << 7;
  const int wr = wid >> 1, wc = wid & 1;
  const int fr = lane & 15, fq = lane >> 4;

  f32x4 acc[2][4];
#pragma unroll
  for (int m = 0; m < 2; ++m)
#pragma unroll
    for (int n = 0; n < 4; ++n) acc[m][n] = (f32x4){0.f, 0.f, 0.f, 0.f};

  for (int k0 = 0; k0 < K; k0 += 64) {
    __syncthreads();
#pragma unroll
    for (int c = 0; c < 2; ++c) {
      int idx = c * 256 + tid;
      int row = idx >> 3, slot = idx & 7;
      As[row * 8 + (slot ^ (row & 7))] =
          *(const uint4*)(A + (size_t)(row0 + row) * K + k0 + slot * 8);
    }
#pragma unroll
    for (int c = 0; c < 4; ++c) {
      int idx = c * 256 + tid;
      int row = idx >> 3, slot = idx & 7;
      Bs[row * 8 + (slot ^ (row & 7))] =
          *(const uint4*)(Bt + (size_t)(col0 + row) * K + k0 + slot * 8);
    }
    __syncthreads();
#pragma unroll
    for (int kk = 0; kk < 2; ++kk) {
      short8 af[2], bfr[4];
#pragma unroll
      for (int m = 0; m < 2; ++m) {
        int row = wr * 32 + m * 16 + fr;
        af[m] = *(const short8*)&As[row * 8 + ((kk * 4 + fq) ^ (row & 7))];
      }
#pragma unroll
      for (int n = 0; n < 4; ++n) {
        int col = wc * 64 + n * 16 + fr;
        bfr[n] = *(const short8*)&Bs[col * 8 + ((kk * 4 + fq) ^ (col & 7))];
      }
#pragma unroll
      for (int m = 0; m < 2; ++m)
#pragma unroll
        for (int n = 0; n < 4; ++n)
          acc[m][n] = __builtin_amdgcn_mfma_f32_16x16x32_bf16(af[m], bfr[n],
                                                              acc[m][n], 0, 0, 0);
    }
  }

#pragma unroll
  for (int n = 0; n < 4; ++n) {
    const int col = col0 + wc * 64 + n * 16 + fr;
    const float bv = BIAS ? bias[col] : 0.f;
#pragma unroll
    for (int m = 0; m < 2; ++m) {
#pragma unroll
      for (int r = 0; r < 4; ++r) {
        int row = row0 + wr * 32 + m * 16 + fq * 4 + r;
        float v = acc[m][n][r];
        if (BIAS) v += bv;
        if (RELU) v = fmaxf(v, 0.f);
        if (OUTBF)
          ((unsigned short*)Cv)[(size_t)row * N + col] = f2bf(v);
        else
          ((float*)Cv)[(size_t)row * N + col] = v;
      }
    }
  }
}

// ---------------------------------------------------------------------------
// gather role: 4 nodes per 256-thread block, one wave each; 4x unrolled
// ---------------------------------------------------------------------------
__device__ __forceinline__ void gather_role(
    int t, const float* __restrict__ node, const float* __restrict__ ef,
    const int2* __restrict__ edges, const int* __restrict__ ofs,
    const float* __restrict__ eps_p, unsigned short* __restrict__ agg16) {
  const int n = t * 4 + (threadIdx.x >> 6);
  const int lane = threadIdx.x & 63;
  const int s0 = ofs[n];
  const int s1 = ofs[n + 1];
  const float epl = 1.f + eps_p[0];
  const f32x4* nodev = (const f32x4*)node;
  const f32x4* efv = (const f32x4*)ef;
  f32x4 xv = nodev[(size_t)n * 64 + lane];
  float a0 = epl * xv.x, a1 = epl * xv.y, a2 = epl * xv.z, a3 = epl * xv.w;
  int j = s0;
  for (; j + 4 <= s1; j += 4) {
    int2 ed0 = edges[j], ed1 = edges[j + 1], ed2 = edges[j + 2],
         ed3 = edges[j + 3];
    f32x4 e0 = __builtin_nontemporal_load(&efv[(size_t)ed0.x * 64 + lane]);
    f32x4 e1 = __builtin_nontemporal_load(&efv[(size_t)ed1.x * 64 + lane]);
    f32x4 e2 = __builtin_nontemporal_load(&efv[(size_t)ed2.x * 64 + lane]);
    f32x4 e3 = __builtin_nontemporal_load(&efv[(size_t)ed3.x * 64 + lane]);
    f32x4 m0 = nodev[(size_t)ed0.y * 64 + lane];
    f32x4 m1 = nodev[(size_t)ed1.y * 64 + lane];
    f32x4 m2 = nodev[(size_t)ed2.y * 64 + lane];
    f32x4 m3 = nodev[(size_t)ed3.y * 64 + lane];
    a0 += fmaxf(e0.x + m0.x, 0.f) + fmaxf(e1.x + m1.x, 0.f) +
          fmaxf(e2.x + m2.x, 0.f) + fmaxf(e3.x + m3.x, 0.f);
    a1 += fmaxf(e0.y + m0.y, 0.f) + fmaxf(e1.y + m1.y, 0.f) +
          fmaxf(e2.y + m2.y, 0.f) + fmaxf(e3.y + m3.y, 0.f);
    a2 += fmaxf(e0.z + m0.z, 0.f) + fmaxf(e1.z + m1.z, 0.f) +
          fmaxf(e2.z + m2.z, 0.f) + fmaxf(e3.z + m3.z, 0.f);
    a3 += fmaxf(e0.w + m0.w, 0.f) + fmaxf(e1.w + m1.w, 0.f) +
          fmaxf(e2.w + m2.w, 0.f) + fmaxf(e3.w + m3.w, 0.f);
  }
  for (; j < s1; ++j) {
    int2 ed = edges[j];
    f32x4 ev = __builtin_nontemporal_load(&efv[(size_t)ed.x * 64 + lane]);
    f32x4 mv = nodev[(size_t)ed.y * 64 + lane];
    a0 += fmaxf(ev.x + mv.x, 0.f);
    a1 += fmaxf(ev.y + mv.y, 0.f);
    a2 += fmaxf(ev.z + mv.z, 0.f);
    a3 += fmaxf(ev.w + mv.w, 0.f);
  }
  ushort4 o;
  o.x = f2bf(a0);
  o.y = f2bf(a1);
  o.z = f2bf(a2);
  o.w = f2bf(a3);
  *(ushort4*)(agg16 + (size_t)n * 256 + lane * 4) = o;
}

// ---------------------------------------------------------------------------
// attn role (proven round-5 MFMA attention), smem passed explicitly
// ---------------------------------------------------------------------------
__device__ __forceinline__ void attn_role(
    int t, char* smemc, const float* __restrict__ aQ,
    const float* __restrict__ aK, const unsigned short* __restrict__ Vp16,
    const float* __restrict__ attn_bias, const int* __restrict__ ptr,
    unsigned short* __restrict__ attn16) {
  unsigned short* Vt = (unsigned short*)smemc;  // 24576 B
  float* aQs = (float*)(smemc + 24576);         // 192
  float* aKs = aQs + 192;
  float* sinv = aKs + 192;
  float* kmax_s = sinv + 192;
  const int b = t >> 2, h = t & 3;
  const int n0 = ptr[b];
  const int tid = threadIdx.x;
  const int wid = tid >> 6, lane = tid & 63;

  if (tid < 192) {
    aQs[tid] = aQ[(size_t)(n0 + tid) * 4 + h];
    aKs[tid] = aK[(size_t)(n0 + tid) * 4 + h];
  }
  for (int i = tid; i < 1536; i += 256) {
    int k = i >> 3, cc = (i & 7) << 3;
    short8 v = *(const short8*)(Vp16 + (size_t)(n0 + k) * 256 + h * 64 + cc);
    int ks = k >> 3, kr = k & 7;
#pragma unroll
    for (int jj = 0; jj < 8; ++jj) {
      int c = cc + jj;
      Vt[c * 192 + ((ks ^ (c & 7)) << 3) + kr] = (unsigned short)v[jj];
    }
  }
  __syncthreads();
  if (wid == 0) {
    float m3 = fmaxf(fmaxf(aKs[lane], aKs[lane + 64]), aKs[lane + 128]);
#pragma unroll
    for (int off = 32; off; off >>= 1) m3 = fmaxf(m3, __shfl_xor(m3, off));
    if (lane == 0) kmax_s[0] = m3;
  }
  __syncthreads();
  const float kmax = kmax_s[0];
  const int fr = lane & 15, fq = lane >> 4;
  const int qbase = wid * 48;

  float aq_m[3], mm[3];
#pragma unroll
  for (int m = 0; m < 3; ++m) {
    float aqv = aQs[qbase + m * 16 + fr];
    aq_m[m] = aqv;
    float tt = aqv + kmax;
    mm[m] = tt > 0.f ? tt : NEG_SLOPE * tt;
  }

  f32x4 acc[3][4];
#pragma unroll
  for (int m = 0; m < 3; ++m)
#pragma unroll
    for (int n = 0; n < 4; ++n) acc[m][n] = (f32x4){0.f, 0.f, 0.f, 0.f};
  float psum[3] = {0.f, 0.f, 0.f};

  for (int ks = 0; ks < 6; ++ks) {
    short8 bf[4];
#pragma unroll
    for (int n = 0; n < 4; ++n) {
      int c = n * 16 + fr;
      bf[n] = *(const short8*)&Vt[c * 192 + ((((ks << 2) + fq) ^ (c & 7)) << 3)];
    }
    float ak[8];
#pragma unroll
    for (int j = 0; j < 8; ++j) ak[j] = aKs[(ks << 5) + (fq << 3) + j];
#pragma unroll
    for (int m = 0; m < 3; ++m) {
      short8 af;
      float ps = 0.f;
#pragma unroll
      for (int j = 0; j < 8; ++j) {
        float x = aq_m[m] + ak[j];
        x = x > 0.f ? x : NEG_SLOPE * x;
        float p = __expf(x - mm[m]);
        ps += p;
        af[j] = (short)f2bf(p);
      }
      psum[m] += ps;
#pragma unroll
      for (int n = 0; n < 4; ++n)
        acc[m][n] =
            __builtin_amdgcn_mfma_f32_16x16x32_bf16(af, bf[n], acc[m][n], 0, 0, 0);
    }
  }

#pragma unroll
  for (int m = 0; m < 3; ++m) {
    psum[m] += __shfl_xor(psum[m], 16);
    psum[m] += __shfl_xor(psum[m], 32);
  }
  if (fq == 0) {
#pragma unroll
    for (int m = 0; m < 3; ++m) sinv[qbase + m * 16 + fr] = 1.f / psum[m];
  }
  __syncthreads();

#pragma unroll
  for (int m = 0; m < 3; ++m) {
#pragma unroll
    for (int n = 0; n < 4; ++n) {
      int col = n * 16 + fr;
      float bv = attn_bias[h * 64 + col];
#pragma unroll
      for (int r = 0; r < 4; ++r) {
        int q = qbase + m * 16 + fq * 4 + r;
        float v = acc[m][n][r] * sinv[q] + bv;
        attn16[(size_t)(n0 + q) * 256 + h * 64 + col] = f2bf(v);
      }
    }
  }
}

// ---------------------------------------------------------------------------
// LN1 role: 4 rows per 256-thread block, bf16 x + f32 res -> bf16 x2[...,256:]
// ---------------------------------------------------------------------------
__device__ __forceinline__ void ln1_role(
    int t, const unsigned short* __restrict__ xin,
    const float* __restrict__ res, const float* __restrict__ g,
    const float* __restrict__ bt, unsigned short* __restrict__ out) {
  const int n = t * 4 + (threadIdx.x >> 6);
  const int lane = threadIdx.x & 63;
  ushort4 xv = *(const ushort4*)(xin + (size_t)n * 256 + lane * 4);
  float v0 = bf2f(xv.x), v1 = bf2f(xv.y), v2 = bf2f(xv.z), v3 = bf2f(xv.w);
  float4 rv = *(const float4*)(res + (size_t)n * 256 + lane * 4);
  v0 += rv.x;
  v1 += rv.y;
  v2 += rv.z;
  v3 += rv.w;
  float s = v0 + v1 + v2 + v3;
  float ss = v0 * v0 + v1 * v1 + v2 * v2 + v3 * v3;
#pragma unroll
  for (int off = 32; off; off >>= 1) {
    s += __shfl_xor(s, off);
    ss += __shfl_xor(ss, off);
  }
  const float mean = s * (1.f / 256.f);
  const float var = ss * (1.f / 256.f) - mean * mean;
  const float rs = rsqrtf(var + LN_EPS);
  float4 gv = *(const float4*)(g + lane * 4);
  float4 bv = *(const float4*)(bt + lane * 4);
  ushort4 o;
  o.x = f2bf((v0 - mean) * rs * gv.x + bv.x);
  o.y = f2bf((v1 - mean) * rs * gv.y + bv.y);
  o.z = f2bf((v2 - mean) * rs * gv.z + bv.z);
  o.w = f2bf((v3 - mean) * rs * gv.w + bv.w);
  *(ushort4*)(out + (size_t)n * 512 + 256 + lane * 4) = o;
}

// ---------------------------------------------------------------------------
// kernels
// ---------------------------------------------------------------------------
__global__ __launch_bounds__(256) void k_fold(
    const float* __restrict__ Wq, const float* __restrict__ Wk,
    const float* __restrict__ alphaQ, const float* __restrict__ alphaK,
    float* __restrict__ wqa, float* __restrict__ wka, int* __restrict__ ideg,
    int Nn) {
  int t = threadIdx.x;
  for (int i = t; i < Nn; i += 256) ideg[i] = 0;
  for (int h = 0; h < 4; ++h) {
    float sq = 0.f, sk = 0.f;
    for (int od = 0; od < 64; ++od) {
      sq += Wq[t * 256 + h * 64 + od] * alphaQ[h * 64 + od];
      sk += Wk[t * 256 + h * 64 + od] * alphaK[h * 64 + od];
    }
    wqa[t * 4 + h] = sq;
    wka[t * 4 + h] = sk;
  }
}

// blocks [0,2048): weight T-casts; [2048,3584): deg atomics; rest: cast+aqk
__global__ __launch_bounds__(256) void k_mega(
    const float* __restrict__ Wv, const float* __restrict__ gW1,
    const float* __restrict__ gW2, const float* __restrict__ fW1,
    const float* __restrict__ fW2, unsigned short* __restrict__ wvt,
    unsigned short* __restrict__ w1t, unsigned short* __restrict__ w2t,
    unsigned short* __restrict__ fw1t, unsigned short* __restrict__ fw2t,
    const int* __restrict__ ei, int* __restrict__ ideg, int E,
    const float* __restrict__ node_feat, unsigned short* __restrict__ nf16,
    const float* __restrict__ wqa, const float* __restrict__ wka,
    float* __restrict__ aQ, float* __restrict__ aK) {
  const int bid = blockIdx.x;
  if (bid < 2048) {
    int i = bid * 256 + threadIdx.x;
    const float* src;
    unsigned short* dst;
    int K, N, base;
    if (i < 65536) {
      src = Wv; dst = wvt; K = 256; N = 256; base = 0;
    } else if (i < 196608) {
      src = gW1; dst = w1t; K = 256; N = 512; base = 65536;
    } else if (i < 327680) {
      src = gW2; dst = w2t; K = 512; N = 256; base = 196608;
    } else if (i < 458752) {
      src = fW1; dst = fw1t; K = 512; N = 256; base = 327680;
    } else {
      src = fW2; dst = fw2t; K = 256; N = 256; base = 458752;
    }
    int j = i - base;
    int n = j / K, k = j - n * K;
    dst[j] = f2bf(src[(size_t)k * N + n]);
    return;
  }
  if (bid < 3584) {
    int e = (bid - 2048) * 256 + threadIdx.x;
    if (e < E) atomicAdd(&ideg[ei[e]], 1);
    return;
  }
  const int n = (bid - 3584) * 4 + (threadIdx.x >> 6);
  const int lane = threadIdx.x & 63;
  f32x4 x = ((const f32x4*)node_feat)[(size_t)n * 64 + lane];
  ushort4 o;
  o.x = f2bf(x.x);
  o.y = f2bf(x.y);
  o.z = f2bf(x.z);
  o.w = f2bf(x.w);
  ((ushort4*)nf16)[(size_t)n * 64 + lane] = o;
  float sq[4], sk[4];
  const int d0 = lane * 4;
#pragma unroll
  for (int h = 0; h < 4; ++h) {
    sq[h] = x.x * wqa[(d0 + 0) * 4 + h] + x.y * wqa[(d0 + 1) * 4 + h] +
            x.z * wqa[(d0 + 2) * 4 + h] + x.w * wqa[(d0 + 3) * 4 + h];
    sk[h] = x.x * wka[(d0 + 0) * 4 + h] + x.y * wka[(d0 + 1) * 4 + h] +
            x.z * wka[(d0 + 2) * 4 + h] + x.w * wka[(d0 + 3) * 4 + h];
  }
#pragma unroll
  for (int off = 32; off; off >>= 1) {
#pragma unroll
    for (int h = 0; h < 4; ++h) {
      sq[h] += __shfl_xor(sq[h], off);
      sk[h] += __shfl_xor(sk[h], off);
    }
  }
  if (lane == 0) {
#pragma unroll
    for (int h = 0; h < 4; ++h) {
      aQ[(size_t)n * 4 + h] = sq[h];
      aK[(size_t)n * 4 + h] = sk[h];
    }
  }
}

__global__ __launch_bounds__(1024) void k_scan(const int* __restrict__ deg,
                                               int* __restrict__ ofs,
                                               int* __restrict__ cursor,
                                               int Nn) {
  __shared__ int part[1024];
  const int t = threadIdx.x;
  const int CH = (Nn + 1023) / 1024;
  const int base = t * CH;
  int s = 0;
  for (int i = 0; i < CH; ++i) s += (base + i < Nn) ? deg[base + i] : 0;
  part[t] = s;
  __syncthreads();
  for (int off = 1; off < 1024; off <<= 1) {
    int v = (t >= off) ? part[t - off] : 0;
    __syncthreads();
    part[t] += v;
    __syncthreads();
  }
  int o = (t == 0) ? 0 : part[t - 1];
  for (int i = 0; i < CH; ++i) {
    if (base + i < Nn) {
      ofs[base + i] = o;
      cursor[base + i] = o;
      o += deg[base + i];
    }
  }
  if (t == 1023) ofs[Nn] = part[1023];
}

__global__ __launch_bounds__(256) void k_scatter(const int* __restrict__ ei,
                                                 int* __restrict__ cursor,
                                                 int2* __restrict__ edges,
                                                 int E) {
  int e = blockIdx.x * 256 + threadIdx.x;
  if (e < E) {
    int src = ei[e];
    int dst = ei[E + e];
    int pos = atomicAdd(&cursor[src], 1);
    edges[pos] = make_int2(e, dst);
  }
}

// Vp GEMM (blocks [0,nbV)) || gather (rest)
__global__ __launch_bounds__(256) void k_gv(
    int nbV, const unsigned short* __restrict__ nf16,
    const unsigned short* __restrict__ wvt, unsigned short* __restrict__ vp16,
    const float* __restrict__ node, const float* __restrict__ ef,
    const int2* __restrict__ edges, const int* __restrict__ ofs,
    const float* __restrict__ eps_p, unsigned short* __restrict__ agg16) {
  __shared__ __align__(16) char smem[24576];
  if ((int)blockIdx.x < nbV)
    gemm_role<false, false, true>(blockIdx.x, smem, nf16, wvt, nullptr, vp16,
                                  256, 256);
  else
    gather_role(blockIdx.x - nbV, node, ef, edges, ofs, eps_p, agg16);
}

// attn (blocks [0,nbA)) || gin-fc1 GEMM (rest)
__global__ __launch_bounds__(256) void k_fa(
    int nbA, const float* __restrict__ aQ, const float* __restrict__ aK,
    const unsigned short* __restrict__ vp16,
    const float* __restrict__ attn_bias, const int* __restrict__ ptr,
    unsigned short* __restrict__ at16, const unsigned short* __restrict__ agg16,
    const unsigned short* __restrict__ w1t, const float* __restrict__ gin_b1,
    unsigned short* __restrict__ t1_16) {
  __shared__ __align__(16) char smem[26944];
  if ((int)blockIdx.x < nbA)
    attn_role(blockIdx.x, smem, aQ, aK, vp16, attn_bias, ptr, at16);
  else
    gemm_role<true, true, true>(blockIdx.x - nbA, smem, agg16, w1t, gin_b1,
                                t1_16, 512, 256);
}

// gin-fc2 GEMM (blocks [0,nbG)) || LN1 (rest)
__global__ __launch_bounds__(256) void k_f2l(
    int nbG, const unsigned short* __restrict__ t1_16,
    const unsigned short* __restrict__ w2t, const float* __restrict__ gin_b2,
    float* __restrict__ buf0, const unsigned short* __restrict__ at16,
    const float* __restrict__ node_feat, const float* __restrict__ g,
    const float* __restrict__ bt, unsigned short* __restrict__ x2_16) {
  __shared__ __align__(16) char smem[24576];
  if ((int)blockIdx.x < nbG)
    gemm_role<false, true, false>(blockIdx.x, smem, t1_16, w2t, gin_b2, buf0,
                                  256, 512);
  else
    ln1_role(blockIdx.x - nbG, at16, node_feat, g, bt, x2_16);
}

// plain GEMM (ff head)
template <bool RELU, bool BIAS, bool OUTBF>
__global__ __launch_bounds__(256) void k_gemm(
    const unsigned short* __restrict__ A, const unsigned short* __restrict__ Bt,
    const float* __restrict__ bias, void* __restrict__ Cv, int N, int K) {
  __shared__ __align__(16) char smem[24576];
  gemm_role<RELU, BIAS, OUTBF>(blockIdx.x, smem, A, Bt, bias, Cv, N, K);
}

// LN2 (f32 input) -> x2[...,0:256]
__global__ __launch_bounds__(64) void k_ln2(
    const float* __restrict__ xin, const float* __restrict__ res,
    const float* __restrict__ g, const float* __restrict__ bt,
    unsigned short* __restrict__ out) {
  const int n = blockIdx.x;
  const int lane = threadIdx.x;
  float4 xv = *(const float4*)(xin + (size_t)n * 256 + lane * 4);
  float4 rv = *(const float4*)(res + (size_t)n * 256 + lane * 4);
  float v0 = xv.x + rv.x, v1 = xv.y + rv.y, v2 = xv.z + rv.z, v3 = xv.w + rv.w;
  float s = v0 + v1 + v2 + v3;
  float ss = v0 * v0 + v1 * v1 + v2 * v2 + v3 * v3;
#pragma unroll
  for (int off = 32; off; off >>= 1) {
    s += __shfl_xor(s, off);
    ss += __shfl_xor(ss, off);
  }
  const float mean = s * (1.f / 256.f);
  const float var = ss * (1.f / 256.f) - mean * mean;
  const float rs = rsqrtf(var + LN_EPS);
  float4 gv = *(const float4*)(g + lane * 4);
  float4 bv = *(const float4*)(bt + lane * 4);
  ushort4 o;
  o.x = f2bf((v0 - mean) * rs * gv.x + bv.x);
  o.y = f2bf((v1 - mean) * rs * gv.y + bv.y);
  o.z = f2bf((v2 - mean) * rs * gv.z + bv.z);
  o.w = f2bf((v3 - mean) * rs * gv.w + bv.w);
  *(ushort4*)(out + (size_t)n * 512 + lane * 4) = o;
}

// ---------------------------------------------------------------------------
extern "C" void kernel_launch(void* const* d_in, const int* in_sizes, int n_in,
                              void* d_out, int out_size, void* d_ws,
                              size_t ws_size, hipStream_t stream) {
  const float* node_feat = (const float*)d_in[0];
  const float* edge_feat = (const float*)d_in[2];
  const int* edge_index = (const int*)d_in[3];
  const int* ptr = (const int*)d_in[5];
  const float* Wq = (const float*)d_in[6];
  const float* Wk = (const float*)d_in[7];
  const float* Wv = (const float*)d_in[8];
  const float* alphaQ = (const float*)d_in[9];
  const float* alphaK = (const float*)d_in[10];
  const float* attn_bias = (const float*)d_in[11];
  const float* gin_eps = (const float*)d_in[12];
  const float* gin_W1 = (const float*)d_in[13];
  const float* gin_b1 = (const float*)d_in[14];
  const float* gin_W2 = (const float*)d_in[15];
  const float* gin_b2 = (const float*)d_in[16];
  const float* ln1_g = (const float*)d_in[17];
  const float* ln1_b = (const float*)d_in[18];
  const float* ln2_g = (const float*)d_in[19];
  const float* ln2_b = (const float*)d_in[20];
  const float* ff_W1 = (const float*)d_in[21];
  const float* ff_b1 = (const float*)d_in[22];
  const float* ff_W2 = (const float*)d_in[23];
  const float* ff_b2 = (const float*)d_in[24];

  const int N = in_sizes[0] / 256;  // 24576
  const int E = in_sizes[2] / 256;  // 393216
  const int B = in_sizes[5] - 1;    // 128

  // workspace layout
  float* ws = (float*)d_ws;
  float* buf0 = ws;                                    // gin fc2 out [N*256] f32
  unsigned short* x2_16 = (unsigned short*)(buf0 + (size_t)N * 256);  // [N*512]
  unsigned short* agg16 = x2_16 + (size_t)N * 512;     // [N*256]
  unsigned short* t1_16 = agg16 + (size_t)N * 256;     // [N*512]
  unsigned short* h1_16 = t1_16 + (size_t)N * 512;     // [N*256]
  unsigned short* nf16 = h1_16 + (size_t)N * 256;      // [N*256]
  unsigned short* vp16 = nf16 + (size_t)N * 256;       // [N*256]
  unsigned short* at16 = vp16 + (size_t)N * 256;       // [N*256]
  unsigned short* wvt = at16 + (size_t)N * 256;        // [256*256]
  unsigned short* w1t = wvt + 65536;                   // [512*256]
  unsigned short* w2t = w1t + 131072;                  // [256*512]
  unsigned short* ffw1t = w2t + 131072;                // [256*512]
  unsigned short* ffw2t = ffw1t + 131072;              // [256*256]
  float* wqa = (float*)(ffw2t + 65536);                // [1024]
  float* wka = wqa + 1024;
  float* aQ = wka + 1024;                  // [N*4]
  float* aK = aQ + (size_t)N * 4;          // [N*4]
  int* ideg = (int*)(aK + (size_t)N * 4);  // [N]
  int* ofs = ideg + N;                     // [N+2]
  int* cursor = ofs + N + 2;               // [N]
  int2* edges = (int2*)(cursor + N);       // [E]
  size_t need = (size_t)N * 256 * 4 + (size_t)N * 2304 * 2 + 1100000 +
                (size_t)N * 8 * 4 + (size_t)N * 16 + (size_t)E * 8 + 8192;
  if (ws_size < need) return;

  const int degB = (E + 255) / 256;  // 1536

  // prep: fold + ideg zero, then mega (weights + deg + cast/aqk)
  k_fold<<<1, 256, 0, stream>>>(Wq, Wk, alphaQ, alphaK, wqa, wka, ideg, N);
  k_mega<<<2048 + degB + N / 4, 256, 0, stream>>>(
      Wv, gin_W1, gin_W2, ff_W1, ff_W2, wvt, w1t, w2t, ffw1t, ffw2t,
      edge_index, ideg, E, node_feat, nf16, wqa, wka, aQ, aK);

  // CSR finish
  k_scan<<<1, 1024, 0, stream>>>(ideg, ofs, cursor, N);
  k_scatter<<<degB, 256, 0, stream>>>(edge_index, cursor, edges, E);

  // Vp GEMM || gather
  const int nbV = (N / 64) * 2;  // 768
  k_gv<<<nbV + N / 4, 256, 0, stream>>>(nbV, nf16, wvt, vp16, node_feat,
                                        edge_feat, edges, ofs, gin_eps, agg16);

  // attn || gin fc1
  const int nbA = B * 4;  // 512
  k_fa<<<nbA + (N / 64) * 4, 256, 0, stream>>>(nbA, aQ, aK, vp16, attn_bias,
                                               ptr, at16, agg16, w1t, gin_b1,
                                               t1_16);

  // gin fc2 || LN1
  const int nbG = (N / 64) * 2;  // 768
  k_f2l<<<nbG + N / 4, 256, 0, stream>>>(nbG, t1_16, w2t, gin_b2, buf0, at16,
                                         node_feat, ln1_g, ln1_b, x2_16);

  // LN2, then FF head
  k_ln2<<<N, 64, 0, stream>>>(buf0, node_feat, ln2_g, ln2_b, x2_16);
  k_gemm<true, true, true><<<(N / 64) * 2, 256, 0, stream>>>(x2_16, ffw1t,
                                                             ff_b1, h1_16, 256,
                                                             512);
  k_gemm<false, true, false><<<(N / 64) * 2, 256, 0, stream>>>(
      h1_16, ffw2t, ff_b2, d_out, 256, 256);
}

// Round 9
// 306.586 us; speedup vs baseline: 1.6358x; 1.0918x over previous
//
#include <hip/hip_runtime.h>

#define LN_EPS 1e-5f
#define NEG_SLOPE 0.2f

typedef __attribute__((ext_vector_type(8))) short short8;
typedef __attribute__((ext_vector_type(4))) float f32x4;

__device__ __forceinline__ unsigned short f2bf(float f) {
  union { float f; unsigned int u; } v;
  v.f = f;
  unsigned int r = v.u + 0x7fffu + ((v.u >> 16) & 1u);
  return (unsigned short)(r >> 16);
}
__device__ __forceinline__ float bf2f(unsigned short u) {
  union { unsigned int u; float f; } v;
  v.u = ((unsigned int)u) << 16;
  return v.f;
}

// ---------------------------------------------------------------------------
// GEMM role: BM=64 x BN=128, BK=64, 16x16x32 MFMA, 24KB LDS, XOR swizzle.
// ---------------------------------------------------------------------------
template <bool RELU, bool BIAS, bool OUTBF>
__device__ __forceinline__ void gemm_role(
    int t, char* smemc, const unsigned short* __restrict__ A,
    const unsigned short* __restrict__ Bt, const float* __restrict__ bias,
    void* __restrict__ Cv, int N, int K) {
  uint4* As = (uint4*)smemc;        // 512 slots
  uint4* Bs = (uint4*)smemc + 512;  // 1024 slots
  const int tid = threadIdx.x;
  const int wid = tid >> 6, lane = tid & 63;
  const int nC = N >> 7;
  const int row0 = (t / nC) << 6;
  const int col0 = (t % nC) << 7;
  const int wr = wid >> 1, wc = wid & 1;
  const int fr = lane & 15, fq = lane >> 4;

  f32x4 acc[2][4];
#pragma unroll
  for (int m = 0; m < 2; ++m)
#pragma unroll
    for (int n = 0; n < 4; ++n) acc[m][n] = (f32x4){0.f, 0.f, 0.f, 0.f};

  for (int k0 = 0; k0 < K; k0 += 64) {
    __syncthreads();
#pragma unroll
    for (int c = 0; c < 2; ++c) {
      int idx = c * 256 + tid;
      int row = idx >> 3, slot = idx & 7;
      As[row * 8 + (slot ^ (row & 7))] =
          *(const uint4*)(A + (size_t)(row0 + row) * K + k0 + slot * 8);
    }
#pragma unroll
    for (int c = 0; c < 4; ++c) {
      int idx = c * 256 + tid;
      int row = idx >> 3, slot = idx & 7;
      Bs[row * 8 + (slot ^ (row & 7))] =
          *(const uint4*)(Bt + (size_t)(col0 + row) * K + k0 + slot * 8);
    }
    __syncthreads();
#pragma unroll
    for (int kk = 0; kk < 2; ++kk) {
      short8 af[2], bfr[4];
#pragma unroll
      for (int m = 0; m < 2; ++m) {
        int row = wr * 32 + m * 16 + fr;
        af[m] = *(const short8*)&As[row * 8 + ((kk * 4 + fq) ^ (row & 7))];
      }
#pragma unroll
      for (int n = 0; n < 4; ++n) {
        int col = wc * 64 + n * 16 + fr;
        bfr[n] = *(const short8*)&Bs[col * 8 + ((kk * 4 + fq) ^ (col & 7))];
      }
#pragma unroll
      for (int m = 0; m < 2; ++m)
#pragma unroll
        for (int n = 0; n < 4; ++n)
          acc[m][n] = __builtin_amdgcn_mfma_f32_16x16x32_bf16(af[m], bfr[n],
                                                              acc[m][n], 0, 0, 0);
    }
  }

#pragma unroll
  for (int n = 0; n < 4; ++n) {
    const int col = col0 + wc * 64 + n * 16 + fr;
    const float bv = BIAS ? bias[col] : 0.f;
#pragma unroll
    for (int m = 0; m < 2; ++m) {
#pragma unroll
      for (int r = 0; r < 4; ++r) {
        int row = row0 + wr * 32 + m * 16 + fq * 4 + r;
        float v = acc[m][n][r];
        if (BIAS) v += bv;
        if (RELU) v = fmaxf(v, 0.f);
        if (OUTBF)
          ((unsigned short*)Cv)[(size_t)row * N + col] = f2bf(v);
        else
          ((float*)Cv)[(size_t)row * N + col] = v;
      }
    }
  }
}

// ---------------------------------------------------------------------------
// gather role: 4 nodes per 256-thread block; dst rows read from bf16 nf16
// (halves L2 footprint of the random gather: 25MB -> 12.5MB)
// ---------------------------------------------------------------------------
__device__ __forceinline__ void gather_role(
    int t, const float* __restrict__ node, const unsigned short* __restrict__ nf16,
    const float* __restrict__ ef, const int2* __restrict__ edges,
    const int* __restrict__ ofs, const float* __restrict__ eps_p,
    unsigned short* __restrict__ agg16) {
  const int n = t * 4 + (threadIdx.x >> 6);
  const int lane = threadIdx.x & 63;
  const int s0 = ofs[n];
  const int s1 = ofs[n + 1];
  const float epl = 1.f + eps_p[0];
  const f32x4* nodev = (const f32x4*)node;
  const f32x4* efv = (const f32x4*)ef;
  const ushort4* nfv = (const ushort4*)nf16;
  f32x4 xv = nodev[(size_t)n * 64 + lane];
  float a0 = epl * xv.x, a1 = epl * xv.y, a2 = epl * xv.z, a3 = epl * xv.w;
  int j = s0;
  for (; j + 4 <= s1; j += 4) {
    int2 ed0 = edges[j], ed1 = edges[j + 1], ed2 = edges[j + 2],
         ed3 = edges[j + 3];
    f32x4 e0 = __builtin_nontemporal_load(&efv[(size_t)ed0.x * 64 + lane]);
    f32x4 e1 = __builtin_nontemporal_load(&efv[(size_t)ed1.x * 64 + lane]);
    f32x4 e2 = __builtin_nontemporal_load(&efv[(size_t)ed2.x * 64 + lane]);
    f32x4 e3 = __builtin_nontemporal_load(&efv[(size_t)ed3.x * 64 + lane]);
    ushort4 m0 = nfv[(size_t)ed0.y * 64 + lane];
    ushort4 m1 = nfv[(size_t)ed1.y * 64 + lane];
    ushort4 m2 = nfv[(size_t)ed2.y * 64 + lane];
    ushort4 m3 = nfv[(size_t)ed3.y * 64 + lane];
    a0 += fmaxf(e0.x + bf2f(m0.x), 0.f) + fmaxf(e1.x + bf2f(m1.x), 0.f) +
          fmaxf(e2.x + bf2f(m2.x), 0.f) + fmaxf(e3.x + bf2f(m3.x), 0.f);
    a1 += fmaxf(e0.y + bf2f(m0.y), 0.f) + fmaxf(e1.y + bf2f(m1.y), 0.f) +
          fmaxf(e2.y + bf2f(m2.y), 0.f) + fmaxf(e3.y + bf2f(m3.y), 0.f);
    a2 += fmaxf(e0.z + bf2f(m0.z), 0.f) + fmaxf(e1.z + bf2f(m1.z), 0.f) +
          fmaxf(e2.z + bf2f(m2.z), 0.f) + fmaxf(e3.z + bf2f(m3.z), 0.f);
    a3 += fmaxf(e0.w + bf2f(m0.w), 0.f) + fmaxf(e1.w + bf2f(m1.w), 0.f) +
          fmaxf(e2.w + bf2f(m2.w), 0.f) + fmaxf(e3.w + bf2f(m3.w), 0.f);
  }
  for (; j < s1; ++j) {
    int2 ed = edges[j];
    f32x4 ev = __builtin_nontemporal_load(&efv[(size_t)ed.x * 64 + lane]);
    ushort4 mv = nfv[(size_t)ed.y * 64 + lane];
    a0 += fmaxf(ev.x + bf2f(mv.x), 0.f);
    a1 += fmaxf(ev.y + bf2f(mv.y), 0.f);
    a2 += fmaxf(ev.z + bf2f(mv.z), 0.f);
    a3 += fmaxf(ev.w + bf2f(mv.w), 0.f);
  }
  ushort4 o;
  o.x = f2bf(a0);
  o.y = f2bf(a1);
  o.z = f2bf(a2);
  o.w = f2bf(a3);
  *(ushort4*)(agg16 + (size_t)n * 256 + lane * 4) = o;
}

// ---------------------------------------------------------------------------
// attn role (proven round-5 MFMA attention)
// ---------------------------------------------------------------------------
__device__ __forceinline__ void attn_role(
    int t, char* smemc, const float* __restrict__ aQ,
    const float* __restrict__ aK, const unsigned short* __restrict__ Vp16,
    const float* __restrict__ attn_bias, const int* __restrict__ ptr,
    unsigned short* __restrict__ attn16) {
  unsigned short* Vt = (unsigned short*)smemc;  // 24576 B
  float* aQs = (float*)(smemc + 24576);         // 192
  float* aKs = aQs + 192;
  float* sinv = aKs + 192;
  float* kmax_s = sinv + 192;
  const int b = t >> 2, h = t & 3;
  const int n0 = ptr[b];
  const int tid = threadIdx.x;
  const int wid = tid >> 6, lane = tid & 63;

  if (tid < 192) {
    aQs[tid] = aQ[(size_t)(n0 + tid) * 4 + h];
    aKs[tid] = aK[(size_t)(n0 + tid) * 4 + h];
  }
  for (int i = tid; i < 1536; i += 256) {
    int k = i >> 3, cc = (i & 7) << 3;
    short8 v = *(const short8*)(Vp16 + (size_t)(n0 + k) * 256 + h * 64 + cc);
    int ks = k >> 3, kr = k & 7;
#pragma unroll
    for (int jj = 0; jj < 8; ++jj) {
      int c = cc + jj;
      Vt[c * 192 + ((ks ^ (c & 7)) << 3) + kr] = (unsigned short)v[jj];
    }
  }
  __syncthreads();
  if (wid == 0) {
    float m3 = fmaxf(fmaxf(aKs[lane], aKs[lane + 64]), aKs[lane + 128]);
#pragma unroll
    for (int off = 32; off; off >>= 1) m3 = fmaxf(m3, __shfl_xor(m3, off));
    if (lane == 0) kmax_s[0] = m3;
  }
  __syncthreads();
  const float kmax = kmax_s[0];
  const int fr = lane & 15, fq = lane >> 4;
  const int qbase = wid * 48;

  float aq_m[3], mm[3];
#pragma unroll
  for (int m = 0; m < 3; ++m) {
    float aqv = aQs[qbase + m * 16 + fr];
    aq_m[m] = aqv;
    float tt = aqv + kmax;
    mm[m] = tt > 0.f ? tt : NEG_SLOPE * tt;
  }

  f32x4 acc[3][4];
#pragma unroll
  for (int m = 0; m < 3; ++m)
#pragma unroll
    for (int n = 0; n < 4; ++n) acc[m][n] = (f32x4){0.f, 0.f, 0.f, 0.f};
  float psum[3] = {0.f, 0.f, 0.f};

  for (int ks = 0; ks < 6; ++ks) {
    short8 bf[4];
#pragma unroll
    for (int n = 0; n < 4; ++n) {
      int c = n * 16 + fr;
      bf[n] = *(const short8*)&Vt[c * 192 + ((((ks << 2) + fq) ^ (c & 7)) << 3)];
    }
    float ak[8];
#pragma unroll
    for (int j = 0; j < 8; ++j) ak[j] = aKs[(ks << 5) + (fq << 3) + j];
#pragma unroll
    for (int m = 0; m < 3; ++m) {
      short8 af;
      float ps = 0.f;
#pragma unroll
      for (int j = 0; j < 8; ++j) {
        float x = aq_m[m] + ak[j];
        x = x > 0.f ? x : NEG_SLOPE * x;
        float p = __expf(x - mm[m]);
        ps += p;
        af[j] = (short)f2bf(p);
      }
      psum[m] += ps;
#pragma unroll
      for (int n = 0; n < 4; ++n)
        acc[m][n] =
            __builtin_amdgcn_mfma_f32_16x16x32_bf16(af, bf[n], acc[m][n], 0, 0, 0);
    }
  }

#pragma unroll
  for (int m = 0; m < 3; ++m) {
    psum[m] += __shfl_xor(psum[m], 16);
    psum[m] += __shfl_xor(psum[m], 32);
  }
  if (fq == 0) {
#pragma unroll
    for (int m = 0; m < 3; ++m) sinv[qbase + m * 16 + fr] = 1.f / psum[m];
  }
  __syncthreads();

#pragma unroll
  for (int m = 0; m < 3; ++m) {
#pragma unroll
    for (int n = 0; n < 4; ++n) {
      int col = n * 16 + fr;
      float bv = attn_bias[h * 64 + col];
#pragma unroll
      for (int r = 0; r < 4; ++r) {
        int q = qbase + m * 16 + fq * 4 + r;
        float v = acc[m][n][r] * sinv[q] + bv;
        attn16[(size_t)(n0 + q) * 256 + h * 64 + col] = f2bf(v);
      }
    }
  }
}

// ---------------------------------------------------------------------------
// fused fc2 + LN2 role: 512 threads, BM=64 x BN=256 (block owns full rows).
// 8 waves 2x4; epilogue computes row stats via shfl + 2KB LDS cross-wave
// reduce, writes normalized bf16 into x2[...,0:256].
// ---------------------------------------------------------------------------
__device__ __forceinline__ void fc2ln_role(
    int t, char* smemc, const unsigned short* __restrict__ A,
    const unsigned short* __restrict__ Bt, const float* __restrict__ b2,
    const float* __restrict__ res, const float* __restrict__ g,
    const float* __restrict__ bln, unsigned short* __restrict__ x2) {
  uint4* As = (uint4*)smemc;         // 512 slots (64 rows x 8)
  uint4* Bs = (uint4*)smemc + 512;   // 2048 slots (256 rows x 8)
  float2* part = (float2*)((uint4*)smemc + 2560);  // [64][4]
  const int tid = threadIdx.x;
  const int wid = tid >> 6, lane = tid & 63;
  const int row0 = t << 6;
  const int wr = wid >> 2, wc = wid & 3;
  const int fr = lane & 15, fq = lane >> 4;
  const int K = 512;

  f32x4 acc[2][4];
#pragma unroll
  for (int m = 0; m < 2; ++m)
#pragma unroll
    for (int n = 0; n < 4; ++n) acc[m][n] = (f32x4){0.f, 0.f, 0.f, 0.f};

  for (int k0 = 0; k0 < K; k0 += 64) {
    __syncthreads();
    {
      int row = tid >> 3, slot = tid & 7;
      As[row * 8 + (slot ^ (row & 7))] =
          *(const uint4*)(A + (size_t)(row0 + row) * K + k0 + slot * 8);
    }
#pragma unroll
    for (int c = 0; c < 4; ++c) {
      int idx = c * 512 + tid;
      int row = idx >> 3, slot = idx & 7;
      Bs[row * 8 + (slot ^ (row & 7))] =
          *(const uint4*)(Bt + (size_t)row * K + k0 + slot * 8);
    }
    __syncthreads();
#pragma unroll
    for (int kk = 0; kk < 2; ++kk) {
      short8 af[2], bfr[4];
#pragma unroll
      for (int m = 0; m < 2; ++m) {
        int row = wr * 32 + m * 16 + fr;
        af[m] = *(const short8*)&As[row * 8 + ((kk * 4 + fq) ^ (row & 7))];
      }
#pragma unroll
      for (int n = 0; n < 4; ++n) {
        int col = wc * 64 + n * 16 + fr;
        bfr[n] = *(const short8*)&Bs[col * 8 + ((kk * 4 + fq) ^ (col & 7))];
      }
#pragma unroll
      for (int m = 0; m < 2; ++m)
#pragma unroll
        for (int n = 0; n < 4; ++n)
          acc[m][n] = __builtin_amdgcn_mfma_f32_16x16x32_bf16(af[m], bfr[n],
                                                              acc[m][n], 0, 0, 0);
    }
  }

  // v = fc2 + bias + residual;  per-(row, wave) partial sums over 64 cols
  float psum[2][4], psq[2][4];
#pragma unroll
  for (int m = 0; m < 2; ++m)
#pragma unroll
    for (int r = 0; r < 4; ++r) {
      psum[m][r] = 0.f;
      psq[m][r] = 0.f;
    }
#pragma unroll
  for (int n = 0; n < 4; ++n) {
    const int col = wc * 64 + n * 16 + fr;
    const float bv = b2[col];
#pragma unroll
    for (int m = 0; m < 2; ++m) {
#pragma unroll
      for (int r = 0; r < 4; ++r) {
        int row = row0 + wr * 32 + m * 16 + fq * 4 + r;
        float v = acc[m][n][r] + bv + res[(size_t)row * 256 + col];
        acc[m][n][r] = v;
        psum[m][r] += v;
        psq[m][r] += v * v;
      }
    }
  }
  // reduce over fr bits (stays within fq group): 64-col wave partials
#pragma unroll
  for (int off = 1; off < 16; off <<= 1) {
#pragma unroll
    for (int m = 0; m < 2; ++m)
#pragma unroll
      for (int r = 0; r < 4; ++r) {
        psum[m][r] += __shfl_xor(psum[m][r], off);
        psq[m][r] += __shfl_xor(psq[m][r], off);
      }
  }
  if (fr == 0) {
#pragma unroll
    for (int m = 0; m < 2; ++m)
#pragma unroll
      for (int r = 0; r < 4; ++r)
        part[(wr * 32 + m * 16 + fq * 4 + r) * 4 + wc] =
            make_float2(psum[m][r], psq[m][r]);
  }
  __syncthreads();

#pragma unroll
  for (int m = 0; m < 2; ++m) {
#pragma unroll
    for (int r = 0; r < 4; ++r) {
      const int lr = wr * 32 + m * 16 + fq * 4 + r;
      float2 p0 = part[lr * 4 + 0], p1 = part[lr * 4 + 1],
             p2 = part[lr * 4 + 2], p3 = part[lr * 4 + 3];
      const float mean = (p0.x + p1.x + p2.x + p3.x) * (1.f / 256.f);
      const float var =
          (p0.y + p1.y + p2.y + p3.y) * (1.f / 256.f) - mean * mean;
      const float rs = rsqrtf(var + LN_EPS);
      const int row = row0 + lr;
#pragma unroll
      for (int n = 0; n < 4; ++n) {
        const int col = wc * 64 + n * 16 + fr;
        float v = (acc[m][n][r] - mean) * rs * g[col] + bln[col];
        x2[(size_t)row * 512 + col] = f2bf(v);
      }
    }
  }
}

// ---------------------------------------------------------------------------
// LN1 role (512-thread blocks): 8 rows per block, one wave per row
// ---------------------------------------------------------------------------
__device__ __forceinline__ void ln1_role(
    int t, const unsigned short* __restrict__ xin,
    const float* __restrict__ res, const float* __restrict__ g,
    const float* __restrict__ bt, unsigned short* __restrict__ out) {
  const int n = t * 8 + (threadIdx.x >> 6);
  const int lane = threadIdx.x & 63;
  ushort4 xv = *(const ushort4*)(xin + (size_t)n * 256 + lane * 4);
  float v0 = bf2f(xv.x), v1 = bf2f(xv.y), v2 = bf2f(xv.z), v3 = bf2f(xv.w);
  float4 rv = *(const float4*)(res + (size_t)n * 256 + lane * 4);
  v0 += rv.x;
  v1 += rv.y;
  v2 += rv.z;
  v3 += rv.w;
  float s = v0 + v1 + v2 + v3;
  float ss = v0 * v0 + v1 * v1 + v2 * v2 + v3 * v3;
#pragma unroll
  for (int off = 32; off; off >>= 1) {
    s += __shfl_xor(s, off);
    ss += __shfl_xor(ss, off);
  }
  const float mean = s * (1.f / 256.f);
  const float var = ss * (1.f / 256.f) - mean * mean;
  const float rs = rsqrtf(var + LN_EPS);
  float4 gv = *(const float4*)(g + lane * 4);
  float4 bv = *(const float4*)(bt + lane * 4);
  ushort4 o;
  o.x = f2bf((v0 - mean) * rs * gv.x + bv.x);
  o.y = f2bf((v1 - mean) * rs * gv.y + bv.y);
  o.z = f2bf((v2 - mean) * rs * gv.z + bv.z);
  o.w = f2bf((v3 - mean) * rs * gv.w + bv.w);
  *(ushort4*)(out + (size_t)n * 512 + 256 + lane * 4) = o;
}

// ---------------------------------------------------------------------------
// kernels
// ---------------------------------------------------------------------------
__global__ __launch_bounds__(256) void k_fold(
    const float* __restrict__ Wq, const float* __restrict__ Wk,
    const float* __restrict__ alphaQ, const float* __restrict__ alphaK,
    float* __restrict__ wqa, float* __restrict__ wka, int* __restrict__ ideg,
    int Nn) {
  int t = threadIdx.x;
  for (int i = t; i < Nn; i += 256) ideg[i] = 0;
  for (int h = 0; h < 4; ++h) {
    float sq = 0.f, sk = 0.f;
    for (int od = 0; od < 64; ++od) {
      sq += Wq[t * 256 + h * 64 + od] * alphaQ[h * 64 + od];
      sk += Wk[t * 256 + h * 64 + od] * alphaK[h * 64 + od];
    }
    wqa[t * 4 + h] = sq;
    wka[t * 4 + h] = sk;
  }
}

__global__ __launch_bounds__(256) void k_mega(
    const float* __restrict__ Wv, const float* __restrict__ gW1,
    const float* __restrict__ gW2, const float* __restrict__ fW1,
    const float* __restrict__ fW2, unsigned short* __restrict__ wvt,
    unsigned short* __restrict__ w1t, unsigned short* __restrict__ w2t,
    unsigned short* __restrict__ fw1t, unsigned short* __restrict__ fw2t,
    const int* __restrict__ ei, int* __restrict__ ideg, int E,
    const float* __restrict__ node_feat, unsigned short* __restrict__ nf16,
    const float* __restrict__ wqa, const float* __restrict__ wka,
    float* __restrict__ aQ, float* __restrict__ aK) {
  const int bid = blockIdx.x;
  if (bid < 2048) {
    int i = bid * 256 + threadIdx.x;
    const float* src;
    unsigned short* dst;
    int K, N, base;
    if (i < 65536) {
      src = Wv; dst = wvt; K = 256; N = 256; base = 0;
    } else if (i < 196608) {
      src = gW1; dst = w1t; K = 256; N = 512; base = 65536;
    } else if (i < 327680) {
      src = gW2; dst = w2t; K = 512; N = 256; base = 196608;
    } else if (i < 458752) {
      src = fW1; dst = fw1t; K = 512; N = 256; base = 327680;
    } else {
      src = fW2; dst = fw2t; K = 256; N = 256; base = 458752;
    }
    int j = i - base;
    int n = j / K, k = j - n * K;
    dst[j] = f2bf(src[(size_t)k * N + n]);
    return;
  }
  if (bid < 3584) {
    int e = (bid - 2048) * 256 + threadIdx.x;
    if (e < E) atomicAdd(&ideg[ei[e]], 1);
    return;
  }
  const int n = (bid - 3584) * 4 + (threadIdx.x >> 6);
  const int lane = threadIdx.x & 63;
  f32x4 x = ((const f32x4*)node_feat)[(size_t)n * 64 + lane];
  ushort4 o;
  o.x = f2bf(x.x);
  o.y = f2bf(x.y);
  o.z = f2bf(x.z);
  o.w = f2bf(x.w);
  ((ushort4*)nf16)[(size_t)n * 64 + lane] = o;
  float sq[4], sk[4];
  const int d0 = lane * 4;
#pragma unroll
  for (int h = 0; h < 4; ++h) {
    sq[h] = x.x * wqa[(d0 + 0) * 4 + h] + x.y * wqa[(d0 + 1) * 4 + h] +
            x.z * wqa[(d0 + 2) * 4 + h] + x.w * wqa[(d0 + 3) * 4 + h];
    sk[h] = x.x * wka[(d0 + 0) * 4 + h] + x.y * wka[(d0 + 1) * 4 + h] +
            x.z * wka[(d0 + 2) * 4 + h] + x.w * wka[(d0 + 3) * 4 + h];
  }
#pragma unroll
  for (int off = 32; off; off >>= 1) {
#pragma unroll
    for (int h = 0; h < 4; ++h) {
      sq[h] += __shfl_xor(sq[h], off);
      sk[h] += __shfl_xor(sk[h], off);
    }
  }
  if (lane == 0) {
#pragma unroll
    for (int h = 0; h < 4; ++h) {
      aQ[(size_t)n * 4 + h] = sq[h];
      aK[(size_t)n * 4 + h] = sk[h];
    }
  }
}

__global__ __launch_bounds__(1024) void k_scan(const int* __restrict__ deg,
                                               int* __restrict__ ofs,
                                               int* __restrict__ cursor,
                                               int Nn) {
  __shared__ int part[1024];
  const int t = threadIdx.x;
  const int CH = (Nn + 1023) / 1024;
  const int base = t * CH;
  int s = 0;
  for (int i = 0; i < CH; ++i) s += (base + i < Nn) ? deg[base + i] : 0;
  part[t] = s;
  __syncthreads();
  for (int off = 1; off < 1024; off <<= 1) {
    int v = (t >= off) ? part[t - off] : 0;
    __syncthreads();
    part[t] += v;
    __syncthreads();
  }
  int o = (t == 0) ? 0 : part[t - 1];
  for (int i = 0; i < CH; ++i) {
    if (base + i < Nn) {
      ofs[base + i] = o;
      cursor[base + i] = o;
      o += deg[base + i];
    }
  }
  if (t == 1023) ofs[Nn] = part[1023];
}

__global__ __launch_bounds__(256) void k_scatter(const int* __restrict__ ei,
                                                 int* __restrict__ cursor,
                                                 int2* __restrict__ edges,
                                                 int E) {
  int e = blockIdx.x * 256 + threadIdx.x;
  if (e < E) {
    int src = ei[e];
    int dst = ei[E + e];
    int pos = atomicAdd(&cursor[src], 1);
    edges[pos] = make_int2(e, dst);
  }
}

// Vp GEMM (blocks [0,nbV)) || gather (rest)
__global__ __launch_bounds__(256) void k_gv(
    int nbV, const unsigned short* __restrict__ nf16,
    const unsigned short* __restrict__ wvt, unsigned short* __restrict__ vp16,
    const float* __restrict__ node, const float* __restrict__ ef,
    const int2* __restrict__ edges, const int* __restrict__ ofs,
    const float* __restrict__ eps_p, unsigned short* __restrict__ agg16) {
  __shared__ __align__(16) char smem[24576];
  if ((int)blockIdx.x < nbV)
    gemm_role<false, false, true>(blockIdx.x, smem, nf16, wvt, nullptr, vp16,
                                  256, 256);
  else
    gather_role(blockIdx.x - nbV, node, nf16, ef, edges, ofs, eps_p, agg16);
}

// attn (blocks [0,nbA)) || gin-fc1 GEMM (rest)
__global__ __launch_bounds__(256) void k_fa(
    int nbA, const float* __restrict__ aQ, const float* __restrict__ aK,
    const unsigned short* __restrict__ vp16,
    const float* __restrict__ attn_bias, const int* __restrict__ ptr,
    unsigned short* __restrict__ at16, const unsigned short* __restrict__ agg16,
    const unsigned short* __restrict__ w1t, const float* __restrict__ gin_b1,
    unsigned short* __restrict__ t1_16) {
  __shared__ __align__(16) char smem[26944];
  if ((int)blockIdx.x < nbA)
    attn_role(blockIdx.x, smem, aQ, aK, vp16, attn_bias, ptr, at16);
  else
    gemm_role<true, true, true>(blockIdx.x - nbA, smem, agg16, w1t, gin_b1,
                                t1_16, 512, 256);
}

// fused fc2+LN2 (blocks [0,nbG)) || LN1 (rest); 512 threads
__global__ __launch_bounds__(512) void k_f2l(
    int nbG, const unsigned short* __restrict__ t1_16,
    const unsigned short* __restrict__ w2t, const float* __restrict__ gin_b2,
    const float* __restrict__ node_feat, const float* __restrict__ ln2_g,
    const float* __restrict__ ln2_b, const unsigned short* __restrict__ at16,
    const float* __restrict__ ln1_g, const float* __restrict__ ln1_b,
    unsigned short* __restrict__ x2_16) {
  __shared__ __align__(16) char smem[43520];  // 40KB tiles + 2KB partials
  if ((int)blockIdx.x < nbG)
    fc2ln_role(blockIdx.x, smem, t1_16, w2t, gin_b2, node_feat, ln2_g, ln2_b,
               x2_16);
  else
    ln1_role(blockIdx.x - nbG, at16, node_feat, ln1_g, ln1_b, x2_16);
}

// plain GEMM (ff head)
template <bool RELU, bool BIAS, bool OUTBF>
__global__ __launch_bounds__(256) void k_gemm(
    const unsigned short* __restrict__ A, const unsigned short* __restrict__ Bt,
    const float* __restrict__ bias, void* __restrict__ Cv, int N, int K) {
  __shared__ __align__(16) char smem[24576];
  gemm_role<RELU, BIAS, OUTBF>(blockIdx.x, smem, A, Bt, bias, Cv, N, K);
}

// ---------------------------------------------------------------------------
extern "C" void kernel_launch(void* const* d_in, const int* in_sizes, int n_in,
                              void* d_out, int out_size, void* d_ws,
                              size_t ws_size, hipStream_t stream) {
  const float* node_feat = (const float*)d_in[0];
  const float* edge_feat = (const float*)d_in[2];
  const int* edge_index = (const int*)d_in[3];
  const int* ptr = (const int*)d_in[5];
  const float* Wq = (const float*)d_in[6];
  const float* Wk = (const float*)d_in[7];
  const float* Wv = (const float*)d_in[8];
  const float* alphaQ = (const float*)d_in[9];
  const float* alphaK = (const float*)d_in[10];
  const float* attn_bias = (const float*)d_in[11];
  const float* gin_eps = (const float*)d_in[12];
  const float* gin_W1 = (const float*)d_in[13];
  const float* gin_b1 = (const float*)d_in[14];
  const float* gin_W2 = (const float*)d_in[15];
  const float* gin_b2 = (const float*)d_in[16];
  const float* ln1_g = (const float*)d_in[17];
  const float* ln1_b = (const float*)d_in[18];
  const float* ln2_g = (const float*)d_in[19];
  const float* ln2_b = (const float*)d_in[20];
  const float* ff_W1 = (const float*)d_in[21];
  const float* ff_b1 = (const float*)d_in[22];
  const float* ff_W2 = (const float*)d_in[23];
  const float* ff_b2 = (const float*)d_in[24];

  const int N = in_sizes[0] / 256;  // 24576
  const int E = in_sizes[2] / 256;  // 393216
  const int B = in_sizes[5] - 1;    // 128

  // workspace layout
  float* ws = (float*)d_ws;
  float* buf0 = ws;                                    // (unused, kept)
  unsigned short* x2_16 = (unsigned short*)(buf0 + (size_t)N * 256);  // [N*512]
  unsigned short* agg16 = x2_16 + (size_t)N * 512;     // [N*256]
  unsigned short* t1_16 = agg16 + (size_t)N * 256;     // [N*512]
  unsigned short* h1_16 = t1_16 + (size_t)N * 512;     // [N*256]
  unsigned short* nf16 = h1_16 + (size_t)N * 256;      // [N*256]
  unsigned short* vp16 = nf16 + (size_t)N * 256;       // [N*256]
  unsigned short* at16 = vp16 + (size_t)N * 256;       // [N*256]
  unsigned short* wvt = at16 + (size_t)N * 256;        // [256*256]
  unsigned short* w1t = wvt + 65536;                   // [512*256]
  unsigned short* w2t = w1t + 131072;                  // [256*512]
  unsigned short* ffw1t = w2t + 131072;                // [256*512]
  unsigned short* ffw2t = ffw1t + 131072;              // [256*256]
  float* wqa = (float*)(ffw2t + 65536);                // [1024]
  float* wka = wqa + 1024;
  float* aQ = wka + 1024;                  // [N*4]
  float* aK = aQ + (size_t)N * 4;          // [N*4]
  int* ideg = (int*)(aK + (size_t)N * 4);  // [N]
  int* ofs = ideg + N;                     // [N+2]
  int* cursor = ofs + N + 2;               // [N]
  int2* edges = (int2*)(cursor + N);       // [E]
  size_t need = (size_t)N * 256 * 4 + (size_t)N * 2304 * 2 + 1100000 +
                (size_t)N * 8 * 4 + (size_t)N * 16 + (size_t)E * 8 + 8192;
  if (ws_size < need) return;

  const int degB = (E + 255) / 256;  // 1536

  // prep: fold + ideg zero, then mega (weights + deg + cast/aqk)
  k_fold<<<1, 256, 0, stream>>>(Wq, Wk, alphaQ, alphaK, wqa, wka, ideg, N);
  k_mega<<<2048 + degB + N / 4, 256, 0, stream>>>(
      Wv, gin_W1, gin_W2, ff_W1, ff_W2, wvt, w1t, w2t, ffw1t, ffw2t,
      edge_index, ideg, E, node_feat, nf16, wqa, wka, aQ, aK);

  // CSR finish
  k_scan<<<1, 1024, 0, stream>>>(ideg, ofs, cursor, N);
  k_scatter<<<degB, 256, 0, stream>>>(edge_index, cursor, edges, E);

  // Vp GEMM || gather
  const int nbV = (N / 64) * 2;  // 768
  k_gv<<<nbV + N / 4, 256, 0, stream>>>(nbV, nf16, wvt, vp16, node_feat,
                                        edge_feat, edges, ofs, gin_eps, agg16);

  // attn || gin fc1
  const int nbA = B * 4;  // 512
  k_fa<<<nbA + (N / 64) * 4, 256, 0, stream>>>(nbA, aQ, aK, vp16, attn_bias,
                                               ptr, at16, agg16, w1t, gin_b1,
                                               t1_16);

  // fused gin-fc2+LN2 || LN1
  const int nbG = N / 64;  // 384
  k_f2l<<<nbG + N / 8, 512, 0, stream>>>(nbG, t1_16, w2t, gin_b2, node_feat,
                                         ln2_g, ln2_b, at16, ln1_g, ln1_b,
                                         x2_16);

  // FF head
  k_gemm<true, true, true><<<(N / 64) * 2, 256, 0, stream>>>(x2_16, ffw1t,
                                                             ff_b1, h1_16, 256,
                                                             512);
  k_gemm<false, true, false><<<(N / 64) * 2, 256, 0, stream>>>(
      h1_16, ffw2t, ff_b2, d_out, 256, 256);
}

// Round 10
// 306.175 us; speedup vs baseline: 1.6380x; 1.0013x over previous
//
#include <hip/hip_runtime.h>

#define LN_EPS 1e-5f
#define NEG_SLOPE 0.2f

typedef __attribute__((ext_vector_type(8))) short short8;
typedef __attribute__((ext_vector_type(4))) float f32x4;

__device__ __forceinline__ unsigned short f2bf(float f) {
  union { float f; unsigned int u; } v;
  v.f = f;
  unsigned int r = v.u + 0x7fffu + ((v.u >> 16) & 1u);
  return (unsigned short)(r >> 16);
}
__device__ __forceinline__ float bf2f(unsigned short u) {
  union { unsigned int u; float f; } v;
  v.u = ((unsigned int)u) << 16;
  return v.f;
}

// async global->LDS, 16B per lane; LDS dest = wave-uniform base + lane*16
__device__ __forceinline__ void gld_lds16(const void* g, void* l) {
  __builtin_amdgcn_global_load_lds(
      (const __attribute__((address_space(1))) unsigned int*)g,
      (__attribute__((address_space(3))) unsigned int*)l, 16, 0, 0);
}

// ---------------------------------------------------------------------------
// GEMM role: BM=64 x BN=128, BK=64, 16x16x32 MFMA, 24KB LDS.
// Staging via global_load_lds: linear LDS dest + pre-swizzled global source
// (content identical to reg-staged XOR layout; read side unchanged).
// ---------------------------------------------------------------------------
template <bool RELU, bool BIAS, bool OUTBF>
__device__ __forceinline__ void gemm_role(
    int t, char* smemc, const unsigned short* __restrict__ A,
    const unsigned short* __restrict__ Bt, const float* __restrict__ bias,
    void* __restrict__ Cv, int N, int K) {
  uint4* As = (uint4*)smemc;        // 512 slots
  uint4* Bs = (uint4*)smemc + 512;  // 1024 slots
  const int tid = threadIdx.x;
  const int wid = tid >> 6, lane = tid & 63;
  const int nC = N >> 7;
  const int row0 = (t / nC) << 6;
  const int col0 = (t % nC) << 7;
  const int wr = wid >> 1, wc = wid & 1;
  const int fr = lane & 15, fq = lane >> 4;

  f32x4 acc[2][4];
#pragma unroll
  for (int m = 0; m < 2; ++m)
#pragma unroll
    for (int n = 0; n < 4; ++n) acc[m][n] = (f32x4){0.f, 0.f, 0.f, 0.f};

  for (int k0 = 0; k0 < K; k0 += 64) {
    __syncthreads();
#pragma unroll
    for (int c = 0; c < 2; ++c) {
      int idx = c * 256 + tid;
      int row = idx >> 3, gs = (idx & 7) ^ (row & 7);
      gld_lds16(A + (size_t)(row0 + row) * K + k0 + gs * 8, As + (idx & ~63));
    }
#pragma unroll
    for (int c = 0; c < 4; ++c) {
      int idx = c * 256 + tid;
      int row = idx >> 3, gs = (idx & 7) ^ (row & 7);
      gld_lds16(Bt + (size_t)(col0 + row) * K + k0 + gs * 8, Bs + (idx & ~63));
    }
    __syncthreads();
#pragma unroll
    for (int kk = 0; kk < 2; ++kk) {
      short8 af[2], bfr[4];
#pragma unroll
      for (int m = 0; m < 2; ++m) {
        int row = wr * 32 + m * 16 + fr;
        af[m] = *(const short8*)&As[row * 8 + ((kk * 4 + fq) ^ (row & 7))];
      }
#pragma unroll
      for (int n = 0; n < 4; ++n) {
        int col = wc * 64 + n * 16 + fr;
        bfr[n] = *(const short8*)&Bs[col * 8 + ((kk * 4 + fq) ^ (col & 7))];
      }
#pragma unroll
      for (int m = 0; m < 2; ++m)
#pragma unroll
        for (int n = 0; n < 4; ++n)
          acc[m][n] = __builtin_amdgcn_mfma_f32_16x16x32_bf16(af[m], bfr[n],
                                                              acc[m][n], 0, 0, 0);
    }
  }

#pragma unroll
  for (int n = 0; n < 4; ++n) {
    const int col = col0 + wc * 64 + n * 16 + fr;
    const float bv = BIAS ? bias[col] : 0.f;
#pragma unroll
    for (int m = 0; m < 2; ++m) {
#pragma unroll
      for (int r = 0; r < 4; ++r) {
        int row = row0 + wr * 32 + m * 16 + fq * 4 + r;
        float v = acc[m][n][r];
        if (BIAS) v += bv;
        if (RELU) v = fmaxf(v, 0.f);
        if (OUTBF)
          ((unsigned short*)Cv)[(size_t)row * N + col] = f2bf(v);
        else
          ((float*)Cv)[(size_t)row * N + col] = v;
      }
    }
  }
}

// ---------------------------------------------------------------------------
// gather role: 4 nodes per 256-thread block; dst rows read from bf16 nf16
// ---------------------------------------------------------------------------
__device__ __forceinline__ void gather_role(
    int t, const float* __restrict__ node, const unsigned short* __restrict__ nf16,
    const float* __restrict__ ef, const int2* __restrict__ edges,
    const int* __restrict__ ofs, const float* __restrict__ eps_p,
    unsigned short* __restrict__ agg16) {
  const int n = t * 4 + (threadIdx.x >> 6);
  const int lane = threadIdx.x & 63;
  const int s0 = ofs[n];
  const int s1 = ofs[n + 1];
  const float epl = 1.f + eps_p[0];
  const f32x4* nodev = (const f32x4*)node;
  const f32x4* efv = (const f32x4*)ef;
  const ushort4* nfv = (const ushort4*)nf16;
  f32x4 xv = nodev[(size_t)n * 64 + lane];
  float a0 = epl * xv.x, a1 = epl * xv.y, a2 = epl * xv.z, a3 = epl * xv.w;
  int j = s0;
  for (; j + 4 <= s1; j += 4) {
    int2 ed0 = edges[j], ed1 = edges[j + 1], ed2 = edges[j + 2],
         ed3 = edges[j + 3];
    f32x4 e0 = __builtin_nontemporal_load(&efv[(size_t)ed0.x * 64 + lane]);
    f32x4 e1 = __builtin_nontemporal_load(&efv[(size_t)ed1.x * 64 + lane]);
    f32x4 e2 = __builtin_nontemporal_load(&efv[(size_t)ed2.x * 64 + lane]);
    f32x4 e3 = __builtin_nontemporal_load(&efv[(size_t)ed3.x * 64 + lane]);
    ushort4 m0 = nfv[(size_t)ed0.y * 64 + lane];
    ushort4 m1 = nfv[(size_t)ed1.y * 64 + lane];
    ushort4 m2 = nfv[(size_t)ed2.y * 64 + lane];
    ushort4 m3 = nfv[(size_t)ed3.y * 64 + lane];
    a0 += fmaxf(e0.x + bf2f(m0.x), 0.f) + fmaxf(e1.x + bf2f(m1.x), 0.f) +
          fmaxf(e2.x + bf2f(m2.x), 0.f) + fmaxf(e3.x + bf2f(m3.x), 0.f);
    a1 += fmaxf(e0.y + bf2f(m0.y), 0.f) + fmaxf(e1.y + bf2f(m1.y), 0.f) +
          fmaxf(e2.y + bf2f(m2.y), 0.f) + fmaxf(e3.y + bf2f(m3.y), 0.f);
    a2 += fmaxf(e0.z + bf2f(m0.z), 0.f) + fmaxf(e1.z + bf2f(m1.z), 0.f) +
          fmaxf(e2.z + bf2f(m2.z), 0.f) + fmaxf(e3.z + bf2f(m3.z), 0.f);
    a3 += fmaxf(e0.w + bf2f(m0.w), 0.f) + fmaxf(e1.w + bf2f(m1.w), 0.f) +
          fmaxf(e2.w + bf2f(m2.w), 0.f) + fmaxf(e3.w + bf2f(m3.w), 0.f);
  }
  for (; j < s1; ++j) {
    int2 ed = edges[j];
    f32x4 ev = __builtin_nontemporal_load(&efv[(size_t)ed.x * 64 + lane]);
    ushort4 mv = nfv[(size_t)ed.y * 64 + lane];
    a0 += fmaxf(ev.x + bf2f(mv.x), 0.f);
    a1 += fmaxf(ev.y + bf2f(mv.y), 0.f);
    a2 += fmaxf(ev.z + bf2f(mv.z), 0.f);
    a3 += fmaxf(ev.w + bf2f(mv.w), 0.f);
  }
  ushort4 o;
  o.x = f2bf(a0);
  o.y = f2bf(a1);
  o.z = f2bf(a2);
  o.w = f2bf(a3);
  *(ushort4*)(agg16 + (size_t)n * 256 + lane * 4) = o;
}

// ---------------------------------------------------------------------------
// attn role (proven round-5 MFMA attention; per-lane LDS scatter, keep as-is)
// ---------------------------------------------------------------------------
__device__ __forceinline__ void attn_role(
    int t, char* smemc, const float* __restrict__ aQ,
    const float* __restrict__ aK, const unsigned short* __restrict__ Vp16,
    const float* __restrict__ attn_bias, const int* __restrict__ ptr,
    unsigned short* __restrict__ attn16) {
  unsigned short* Vt = (unsigned short*)smemc;  // 24576 B
  float* aQs = (float*)(smemc + 24576);         // 192
  float* aKs = aQs + 192;
  float* sinv = aKs + 192;
  float* kmax_s = sinv + 192;
  const int b = t >> 2, h = t & 3;
  const int n0 = ptr[b];
  const int tid = threadIdx.x;
  const int wid = tid >> 6, lane = tid & 63;

  if (tid < 192) {
    aQs[tid] = aQ[(size_t)(n0 + tid) * 4 + h];
    aKs[tid] = aK[(size_t)(n0 + tid) * 4 + h];
  }
  for (int i = tid; i < 1536; i += 256) {
    int k = i >> 3, cc = (i & 7) << 3;
    short8 v = *(const short8*)(Vp16 + (size_t)(n0 + k) * 256 + h * 64 + cc);
    int ks = k >> 3, kr = k & 7;
#pragma unroll
    for (int jj = 0; jj < 8; ++jj) {
      int c = cc + jj;
      Vt[c * 192 + ((ks ^ (c & 7)) << 3) + kr] = (unsigned short)v[jj];
    }
  }
  __syncthreads();
  if (wid == 0) {
    float m3 = fmaxf(fmaxf(aKs[lane], aKs[lane + 64]), aKs[lane + 128]);
#pragma unroll
    for (int off = 32; off; off >>= 1) m3 = fmaxf(m3, __shfl_xor(m3, off));
    if (lane == 0) kmax_s[0] = m3;
  }
  __syncthreads();
  const float kmax = kmax_s[0];
  const int fr = lane & 15, fq = lane >> 4;
  const int qbase = wid * 48;

  float aq_m[3], mm[3];
#pragma unroll
  for (int m = 0; m < 3; ++m) {
    float aqv = aQs[qbase + m * 16 + fr];
    aq_m[m] = aqv;
    float tt = aqv + kmax;
    mm[m] = tt > 0.f ? tt : NEG_SLOPE * tt;
  }

  f32x4 acc[3][4];
#pragma unroll
  for (int m = 0; m < 3; ++m)
#pragma unroll
    for (int n = 0; n < 4; ++n) acc[m][n] = (f32x4){0.f, 0.f, 0.f, 0.f};
  float psum[3] = {0.f, 0.f, 0.f};

  for (int ks = 0; ks < 6; ++ks) {
    short8 bf[4];
#pragma unroll
    for (int n = 0; n < 4; ++n) {
      int c = n * 16 + fr;
      bf[n] = *(const short8*)&Vt[c * 192 + ((((ks << 2) + fq) ^ (c & 7)) << 3)];
    }
    float ak[8];
#pragma unroll
    for (int j = 0; j < 8; ++j) ak[j] = aKs[(ks << 5) + (fq << 3) + j];
#pragma unroll
    for (int m = 0; m < 3; ++m) {
      short8 af;
      float ps = 0.f;
#pragma unroll
      for (int j = 0; j < 8; ++j) {
        float x = aq_m[m] + ak[j];
        x = x > 0.f ? x : NEG_SLOPE * x;
        float p = __expf(x - mm[m]);
        ps += p;
        af[j] = (short)f2bf(p);
      }
      psum[m] += ps;
#pragma unroll
      for (int n = 0; n < 4; ++n)
        acc[m][n] =
            __builtin_amdgcn_mfma_f32_16x16x32_bf16(af, bf[n], acc[m][n], 0, 0, 0);
    }
  }

#pragma unroll
  for (int m = 0; m < 3; ++m) {
    psum[m] += __shfl_xor(psum[m], 16);
    psum[m] += __shfl_xor(psum[m], 32);
  }
  if (fq == 0) {
#pragma unroll
    for (int m = 0; m < 3; ++m) sinv[qbase + m * 16 + fr] = 1.f / psum[m];
  }
  __syncthreads();

#pragma unroll
  for (int m = 0; m < 3; ++m) {
#pragma unroll
    for (int n = 0; n < 4; ++n) {
      int col = n * 16 + fr;
      float bv = attn_bias[h * 64 + col];
#pragma unroll
      for (int r = 0; r < 4; ++r) {
        int q = qbase + m * 16 + fq * 4 + r;
        float v = acc[m][n][r] * sinv[q] + bv;
        attn16[(size_t)(n0 + q) * 256 + h * 64 + col] = f2bf(v);
      }
    }
  }
}

// ---------------------------------------------------------------------------
// fused fc2 + LN2 role: 512 threads, BM=64 x BN=256; gload_lds staging
// ---------------------------------------------------------------------------
__device__ __forceinline__ void fc2ln_role(
    int t, char* smemc, const unsigned short* __restrict__ A,
    const unsigned short* __restrict__ Bt, const float* __restrict__ b2,
    const float* __restrict__ res, const float* __restrict__ g,
    const float* __restrict__ bln, unsigned short* __restrict__ x2) {
  uint4* As = (uint4*)smemc;         // 512 slots (64 rows x 8)
  uint4* Bs = (uint4*)smemc + 512;   // 2048 slots (256 rows x 8)
  float2* part = (float2*)((uint4*)smemc + 2560);  // [64][4]
  const int tid = threadIdx.x;
  const int wid = tid >> 6, lane = tid & 63;
  const int row0 = t << 6;
  const int wr = wid >> 2, wc = wid & 3;
  const int fr = lane & 15, fq = lane >> 4;
  const int K = 512;

  f32x4 acc[2][4];
#pragma unroll
  for (int m = 0; m < 2; ++m)
#pragma unroll
    for (int n = 0; n < 4; ++n) acc[m][n] = (f32x4){0.f, 0.f, 0.f, 0.f};

  for (int k0 = 0; k0 < K; k0 += 64) {
    __syncthreads();
    {
      int row = tid >> 3, gs = (tid & 7) ^ (row & 7);
      gld_lds16(A + (size_t)(row0 + row) * K + k0 + gs * 8, As + (tid & ~63));
    }
#pragma unroll
    for (int c = 0; c < 4; ++c) {
      int idx = c * 512 + tid;
      int row = idx >> 3, gs = (idx & 7) ^ (row & 7);
      gld_lds16(Bt + (size_t)row * K + k0 + gs * 8, Bs + (idx & ~63));
    }
    __syncthreads();
#pragma unroll
    for (int kk = 0; kk < 2; ++kk) {
      short8 af[2], bfr[4];
#pragma unroll
      for (int m = 0; m < 2; ++m) {
        int row = wr * 32 + m * 16 + fr;
        af[m] = *(const short8*)&As[row * 8 + ((kk * 4 + fq) ^ (row & 7))];
      }
#pragma unroll
      for (int n = 0; n < 4; ++n) {
        int col = wc * 64 + n * 16 + fr;
        bfr[n] = *(const short8*)&Bs[col * 8 + ((kk * 4 + fq) ^ (col & 7))];
      }
#pragma unroll
      for (int m = 0; m < 2; ++m)
#pragma unroll
        for (int n = 0; n < 4; ++n)
          acc[m][n] = __builtin_amdgcn_mfma_f32_16x16x32_bf16(af[m], bfr[n],
                                                              acc[m][n], 0, 0, 0);
    }
  }

  float psum[2][4], psq[2][4];
#pragma unroll
  for (int m = 0; m < 2; ++m)
#pragma unroll
    for (int r = 0; r < 4; ++r) {
      psum[m][r] = 0.f;
      psq[m][r] = 0.f;
    }
#pragma unroll
  for (int n = 0; n < 4; ++n) {
    const int col = wc * 64 + n * 16 + fr;
    const float bv = b2[col];
#pragma unroll
    for (int m = 0; m < 2; ++m) {
#pragma unroll
      for (int r = 0; r < 4; ++r) {
        int row = row0 + wr * 32 + m * 16 + fq * 4 + r;
        float v = acc[m][n][r] + bv + res[(size_t)row * 256 + col];
        acc[m][n][r] = v;
        psum[m][r] += v;
        psq[m][r] += v * v;
      }
    }
  }
#pragma unroll
  for (int off = 1; off < 16; off <<= 1) {
#pragma unroll
    for (int m = 0; m < 2; ++m)
#pragma unroll
      for (int r = 0; r < 4; ++r) {
        psum[m][r] += __shfl_xor(psum[m][r], off);
        psq[m][r] += __shfl_xor(psq[m][r], off);
      }
  }
  if (fr == 0) {
#pragma unroll
    for (int m = 0; m < 2; ++m)
#pragma unroll
      for (int r = 0; r < 4; ++r)
        part[(wr * 32 + m * 16 + fq * 4 + r) * 4 + wc] =
            make_float2(psum[m][r], psq[m][r]);
  }
  __syncthreads();

#pragma unroll
  for (int m = 0; m < 2; ++m) {
#pragma unroll
    for (int r = 0; r < 4; ++r) {
      const int lr = wr * 32 + m * 16 + fq * 4 + r;
      float2 p0 = part[lr * 4 + 0], p1 = part[lr * 4 + 1],
             p2 = part[lr * 4 + 2], p3 = part[lr * 4 + 3];
      const float mean = (p0.x + p1.x + p2.x + p3.x) * (1.f / 256.f);
      const float var =
          (p0.y + p1.y + p2.y + p3.y) * (1.f / 256.f) - mean * mean;
      const float rs = rsqrtf(var + LN_EPS);
      const int row = row0 + lr;
#pragma unroll
      for (int n = 0; n < 4; ++n) {
        const int col = wc * 64 + n * 16 + fr;
        float v = (acc[m][n][r] - mean) * rs * g[col] + bln[col];
        x2[(size_t)row * 512 + col] = f2bf(v);
      }
    }
  }
}

// ---------------------------------------------------------------------------
// LN1 role (512-thread blocks): 8 rows per block, one wave per row
// ---------------------------------------------------------------------------
__device__ __forceinline__ void ln1_role(
    int t, const unsigned short* __restrict__ xin,
    const float* __restrict__ res, const float* __restrict__ g,
    const float* __restrict__ bt, unsigned short* __restrict__ out) {
  const int n = t * 8 + (threadIdx.x >> 6);
  const int lane = threadIdx.x & 63;
  ushort4 xv = *(const ushort4*)(xin + (size_t)n * 256 + lane * 4);
  float v0 = bf2f(xv.x), v1 = bf2f(xv.y), v2 = bf2f(xv.z), v3 = bf2f(xv.w);
  float4 rv = *(const float4*)(res + (size_t)n * 256 + lane * 4);
  v0 += rv.x;
  v1 += rv.y;
  v2 += rv.z;
  v3 += rv.w;
  float s = v0 + v1 + v2 + v3;
  float ss = v0 * v0 + v1 * v1 + v2 * v2 + v3 * v3;
#pragma unroll
  for (int off = 32; off; off >>= 1) {
    s += __shfl_xor(s, off);
    ss += __shfl_xor(ss, off);
  }
  const float mean = s * (1.f / 256.f);
  const float var = ss * (1.f / 256.f) - mean * mean;
  const float rs = rsqrtf(var + LN_EPS);
  float4 gv = *(const float4*)(g + lane * 4);
  float4 bv = *(const float4*)(bt + lane * 4);
  ushort4 o;
  o.x = f2bf((v0 - mean) * rs * gv.x + bv.x);
  o.y = f2bf((v1 - mean) * rs * gv.y + bv.y);
  o.z = f2bf((v2 - mean) * rs * gv.z + bv.z);
  o.w = f2bf((v3 - mean) * rs * gv.w + bv.w);
  *(ushort4*)(out + (size_t)n * 512 + 256 + lane * 4) = o;
}

// ---------------------------------------------------------------------------
// kernels
// ---------------------------------------------------------------------------
__global__ __launch_bounds__(256) void k_fold(
    const float* __restrict__ Wq, const float* __restrict__ Wk,
    const float* __restrict__ alphaQ, const float* __restrict__ alphaK,
    float* __restrict__ wqa, float* __restrict__ wka, int* __restrict__ ideg,
    int Nn) {
  int t = threadIdx.x;
  for (int i = t; i < Nn; i += 256) ideg[i] = 0;
  for (int h = 0; h < 4; ++h) {
    float sq = 0.f, sk = 0.f;
    for (int od = 0; od < 64; ++od) {
      sq += Wq[t * 256 + h * 64 + od] * alphaQ[h * 64 + od];
      sk += Wk[t * 256 + h * 64 + od] * alphaK[h * 64 + od];
    }
    wqa[t * 4 + h] = sq;
    wka[t * 4 + h] = sk;
  }
}

__global__ __launch_bounds__(256) void k_mega(
    const float* __restrict__ Wv, const float* __restrict__ gW1,
    const float* __restrict__ gW2, const float* __restrict__ fW1,
    const float* __restrict__ fW2, unsigned short* __restrict__ wvt,
    unsigned short* __restrict__ w1t, unsigned short* __restrict__ w2t,
    unsigned short* __restrict__ fw1t, unsigned short* __restrict__ fw2t,
    const int* __restrict__ ei, int* __restrict__ ideg, int E,
    const float* __restrict__ node_feat, unsigned short* __restrict__ nf16,
    const float* __restrict__ wqa, const float* __restrict__ wka,
    float* __restrict__ aQ, float* __restrict__ aK) {
  const int bid = blockIdx.x;
  if (bid < 2048) {
    int i = bid * 256 + threadIdx.x;
    const float* src;
    unsigned short* dst;
    int K, N, base;
    if (i < 65536) {
      src = Wv; dst = wvt; K = 256; N = 256; base = 0;
    } else if (i < 196608) {
      src = gW1; dst = w1t; K = 256; N = 512; base = 65536;
    } else if (i < 327680) {
      src = gW2; dst = w2t; K = 512; N = 256; base = 196608;
    } else if (i < 458752) {
      src = fW1; dst = fw1t; K = 512; N = 256; base = 327680;
    } else {
      src = fW2; dst = fw2t; K = 256; N = 256; base = 458752;
    }
    int j = i - base;
    int n = j / K, k = j - n * K;
    dst[j] = f2bf(src[(size_t)k * N + n]);
    return;
  }
  if (bid < 3584) {
    int e = (bid - 2048) * 256 + threadIdx.x;
    if (e < E) atomicAdd(&ideg[ei[e]], 1);
    return;
  }
  const int n = (bid - 3584) * 4 + (threadIdx.x >> 6);
  const int lane = threadIdx.x & 63;
  f32x4 x = ((const f32x4*)node_feat)[(size_t)n * 64 + lane];
  ushort4 o;
  o.x = f2bf(x.x);
  o.y = f2bf(x.y);
  o.z = f2bf(x.z);
  o.w = f2bf(x.w);
  ((ushort4*)nf16)[(size_t)n * 64 + lane] = o;
  float sq[4], sk[4];
  const int d0 = lane * 4;
#pragma unroll
  for (int h = 0; h < 4; ++h) {
    sq[h] = x.x * wqa[(d0 + 0) * 4 + h] + x.y * wqa[(d0 + 1) * 4 + h] +
            x.z * wqa[(d0 + 2) * 4 + h] + x.w * wqa[(d0 + 3) * 4 + h];
    sk[h] = x.x * wka[(d0 + 0) * 4 + h] + x.y * wka[(d0 + 1) * 4 + h] +
            x.z * wka[(d0 + 2) * 4 + h] + x.w * wka[(d0 + 3) * 4 + h];
  }
#pragma unroll
  for (int off = 32; off; off >>= 1) {
#pragma unroll
    for (int h = 0; h < 4; ++h) {
      sq[h] += __shfl_xor(sq[h], off);
      sk[h] += __shfl_xor(sk[h], off);
    }
  }
  if (lane == 0) {
#pragma unroll
    for (int h = 0; h < 4; ++h) {
      aQ[(size_t)n * 4 + h] = sq[h];
      aK[(size_t)n * 4 + h] = sk[h];
    }
  }
}

__global__ __launch_bounds__(1024) void k_scan(const int* __restrict__ deg,
                                               int* __restrict__ ofs,
                                               int* __restrict__ cursor,
                                               int Nn) {
  __shared__ int part[1024];
  const int t = threadIdx.x;
  const int CH = (Nn + 1023) / 1024;
  const int base = t * CH;
  int s = 0;
  for (int i = 0; i < CH; ++i) s += (base + i < Nn) ? deg[base + i] : 0;
  part[t] = s;
  __syncthreads();
  for (int off = 1; off < 1024; off <<= 1) {
    int v = (t >= off) ? part[t - off] : 0;
    __syncthreads();
    part[t] += v;
    __syncthreads();
  }
  int o = (t == 0) ? 0 : part[t - 1];
  for (int i = 0; i < CH; ++i) {
    if (base + i < Nn) {
      ofs[base + i] = o;
      cursor[base + i] = o;
      o += deg[base + i];
    }
  }
  if (t == 1023) ofs[Nn] = part[1023];
}

__global__ __launch_bounds__(256) void k_scatter(const int* __restrict__ ei,
                                                 int* __restrict__ cursor,
                                                 int2* __restrict__ edges,
                                                 int E) {
  int e = blockIdx.x * 256 + threadIdx.x;
  if (e < E) {
    int src = ei[e];
    int dst = ei[E + e];
    int pos = atomicAdd(&cursor[src], 1);
    edges[pos] = make_int2(e, dst);
  }
}

// Vp GEMM (blocks [0,nbV)) || gather (rest)
__global__ __launch_bounds__(256) void k_gv(
    int nbV, const unsigned short* __restrict__ nf16,
    const unsigned short* __restrict__ wvt, unsigned short* __restrict__ vp16,
    const float* __restrict__ node, const float* __restrict__ ef,
    const int2* __restrict__ edges, const int* __restrict__ ofs,
    const float* __restrict__ eps_p, unsigned short* __restrict__ agg16) {
  __shared__ __align__(16) char smem[24576];
  if ((int)blockIdx.x < nbV)
    gemm_role<false, false, true>(blockIdx.x, smem, nf16, wvt, nullptr, vp16,
                                  256, 256);
  else
    gather_role(blockIdx.x - nbV, node, nf16, ef, edges, ofs, eps_p, agg16);
}

// attn (blocks [0,nbA)) || gin-fc1 GEMM (rest)
__global__ __launch_bounds__(256) void k_fa(
    int nbA, const float* __restrict__ aQ, const float* __restrict__ aK,
    const unsigned short* __restrict__ vp16,
    const float* __restrict__ attn_bias, const int* __restrict__ ptr,
    unsigned short* __restrict__ at16, const unsigned short* __restrict__ agg16,
    const unsigned short* __restrict__ w1t, const float* __restrict__ gin_b1,
    unsigned short* __restrict__ t1_16) {
  __shared__ __align__(16) char smem[26944];
  if ((int)blockIdx.x < nbA)
    attn_role(blockIdx.x, smem, aQ, aK, vp16, attn_bias, ptr, at16);
  else
    gemm_role<true, true, true>(blockIdx.x - nbA, smem, agg16, w1t, gin_b1,
                                t1_16, 512, 256);
}

// fused fc2+LN2 (blocks [0,nbG)) || LN1 (rest); 512 threads
__global__ __launch_bounds__(512) void k_f2l(
    int nbG, const unsigned short* __restrict__ t1_16,
    const unsigned short* __restrict__ w2t, const float* __restrict__ gin_b2,
    const float* __restrict__ node_feat, const float* __restrict__ ln2_g,
    const float* __restrict__ ln2_b, const unsigned short* __restrict__ at16,
    const float* __restrict__ ln1_g, const float* __restrict__ ln1_b,
    unsigned short* __restrict__ x2_16) {
  __shared__ __align__(16) char smem[43520];  // 40KB tiles + 2KB partials
  if ((int)blockIdx.x < nbG)
    fc2ln_role(blockIdx.x, smem, t1_16, w2t, gin_b2, node_feat, ln2_g, ln2_b,
               x2_16);
  else
    ln1_role(blockIdx.x - nbG, at16, node_feat, ln1_g, ln1_b, x2_16);
}

// plain GEMM (ff head)
template <bool RELU, bool BIAS, bool OUTBF>
__global__ __launch_bounds__(256) void k_gemm(
    const unsigned short* __restrict__ A, const unsigned short* __restrict__ Bt,
    const float* __restrict__ bias, void* __restrict__ Cv, int N, int K) {
  __shared__ __align__(16) char smem[24576];
  gemm_role<RELU, BIAS, OUTBF>(blockIdx.x, smem, A, Bt, bias, Cv, N, K);
}

// ---------------------------------------------------------------------------
extern "C" void kernel_launch(void* const* d_in, const int* in_sizes, int n_in,
                              void* d_out, int out_size, void* d_ws,
                              size_t ws_size, hipStream_t stream) {
  const float* node_feat = (const float*)d_in[0];
  const float* edge_feat = (const float*)d_in[2];
  const int* edge_index = (const int*)d_in[3];
  const int* ptr = (const int*)d_in[5];
  const float* Wq = (const float*)d_in[6];
  const float* Wk = (const float*)d_in[7];
  const float* Wv = (const float*)d_in[8];
  const float* alphaQ = (const float*)d_in[9];
  const float* alphaK = (const float*)d_in[10];
  const float* attn_bias = (const float*)d_in[11];
  const float* gin_eps = (const float*)d_in[12];
  const float* gin_W1 = (const float*)d_in[13];
  const float* gin_b1 = (const float*)d_in[14];
  const float* gin_W2 = (const float*)d_in[15];
  const float* gin_b2 = (const float*)d_in[16];
  const float* ln1_g = (const float*)d_in[17];
  const float* ln1_b = (const float*)d_in[18];
  const float* ln2_g = (const float*)d_in[19];
  const float* ln2_b = (const float*)d_in[20];
  const float* ff_W1 = (const float*)d_in[21];
  const float* ff_b1 = (const float*)d_in[22];
  const float* ff_W2 = (const float*)d_in[23];
  const float* ff_b2 = (const float*)d_in[24];

  const int N = in_sizes[0] / 256;  // 24576
  const int E = in_sizes[2] / 256;  // 393216
  const int B = in_sizes[5] - 1;    // 128

  // workspace layout
  float* ws = (float*)d_ws;
  float* buf0 = ws;                                    // (unused, kept)
  unsigned short* x2_16 = (unsigned short*)(buf0 + (size_t)N * 256);  // [N*512]
  unsigned short* agg16 = x2_16 + (size_t)N * 512;     // [N*256]
  unsigned short* t1_16 = agg16 + (size_t)N * 256;     // [N*512]
  unsigned short* h1_16 = t1_16 + (size_t)N * 512;     // [N*256]
  unsigned short* nf16 = h1_16 + (size_t)N * 256;      // [N*256]
  unsigned short* vp16 = nf16 + (size_t)N * 256;       // [N*256]
  unsigned short* at16 = vp16 + (size_t)N * 256;       // [N*256]
  unsigned short* wvt = at16 + (size_t)N * 256;        // [256*256]
  unsigned short* w1t = wvt + 65536;                   // [512*256]
  unsigned short* w2t = w1t + 131072;                  // [256*512]
  unsigned short* ffw1t = w2t + 131072;                // [256*512]
  unsigned short* ffw2t = ffw1t + 131072;              // [256*256]
  float* wqa = (float*)(ffw2t + 65536);                // [1024]
  float* wka = wqa + 1024;
  float* aQ = wka + 1024;                  // [N*4]
  float* aK = aQ + (size_t)N * 4;          // [N*4]
  int* ideg = (int*)(aK + (size_t)N * 4);  // [N]
  int* ofs = ideg + N;                     // [N+2]
  int* cursor = ofs + N + 2;               // [N]
  int2* edges = (int2*)(cursor + N);       // [E]
  size_t need = (size_t)N * 256 * 4 + (size_t)N * 2304 * 2 + 1100000 +
                (size_t)N * 8 * 4 + (size_t)N * 16 + (size_t)E * 8 + 8192;
  if (ws_size < need) return;

  const int degB = (E + 255) / 256;  // 1536

  // prep: fold + ideg zero, then mega (weights + deg + cast/aqk)
  k_fold<<<1, 256, 0, stream>>>(Wq, Wk, alphaQ, alphaK, wqa, wka, ideg, N);
  k_mega<<<2048 + degB + N / 4, 256, 0, stream>>>(
      Wv, gin_W1, gin_W2, ff_W1, ff_W2, wvt, w1t, w2t, ffw1t, ffw2t,
      edge_index, ideg, E, node_feat, nf16, wqa, wka, aQ, aK);

  // CSR finish
  k_scan<<<1, 1024, 0, stream>>>(ideg, ofs, cursor, N);
  k_scatter<<<degB, 256, 0, stream>>>(edge_index, cursor, edges, E);

  // Vp GEMM || gather
  const int nbV = (N / 64) * 2;  // 768
  k_gv<<<nbV + N / 4, 256, 0, stream>>>(nbV, nf16, wvt, vp16, node_feat,
                                        edge_feat, edges, ofs, gin_eps, agg16);

  // attn || gin fc1
  const int nbA = B * 4;  // 512
  k_fa<<<nbA + (N / 64) * 4, 256, 0, stream>>>(nbA, aQ, aK, vp16, attn_bias,
                                               ptr, at16, agg16, w1t, gin_b1,
                                               t1_16);

  // fused gin-fc2+LN2 || LN1
  const int nbG = N / 64;  // 384
  k_f2l<<<nbG + N / 8, 512, 0, stream>>>(nbG, t1_16, w2t, gin_b2, node_feat,
                                         ln2_g, ln2_b, at16, ln1_g, ln1_b,
                                         x2_16);

  // FF head
  k_gemm<true, true, true><<<(N / 64) * 2, 256, 0, stream>>>(x2_16, ffw1t,
                                                             ff_b1, h1_16, 256,
                                                             512);
  k_gemm<false, true, false><<<(N / 64) * 2, 256, 0, stream>>>(
      h1_16, ffw2t, ff_b2, d_out, 256, 256);
}